// Round 5
// baseline (686.390 us; speedup 1.0000x reference)
//
#include <hip/hip_runtime.h>
#include <hip/hip_bf16.h>
#include <cstdint>

#define NN 100000
#define NE 1600000
#define NC 128

constexpr int SCAN_SEG = 1024;
constexpr int NB = (NN + SCAN_SEG - 1) / SCAN_SEG; // 98

// ---------------- CSR build ----------------

__global__ __launch_bounds__(256) void k_init(int* __restrict__ cnt) {
    int i = blockIdx.x * 256 + threadIdx.x;
    if (i < NN) cnt[i] = 0;
}

// one int atomic per edge; returned old value = within-row slot. 4 edges/thread.
__global__ __launch_bounds__(256) void k_count(const int4* __restrict__ dst4, int* __restrict__ cnt,
                                               int4* __restrict__ slot4) {
    int i = blockIdx.x * 256 + threadIdx.x;
    if (i < NE / 4) {
        int4 d = dst4[i];
        int4 s;
        s.x = atomicAdd(&cnt[d.x], 1);
        s.y = atomicAdd(&cnt[d.y], 1);
        s.z = atomicAdd(&cnt[d.z], 1);
        s.w = atomicAdd(&cnt[d.w], 1);
        slot4[i] = s;
    }
}

// ---------------- exclusive scan of cnt -> rowstart ----------------

__global__ __launch_bounds__(256) void k_scan1(const int* __restrict__ cnt, int* __restrict__ bsum) {
    __shared__ int sdata[256];
    int b = blockIdx.x, t = threadIdx.x;
    int base = b * SCAN_SEG + t * 4;
    int s = 0;
    #pragma unroll
    for (int j = 0; j < 4; ++j) { int idx = base + j; if (idx < NN) s += cnt[idx]; }
    sdata[t] = s; __syncthreads();
    for (int off = 128; off > 0; off >>= 1) {
        if (t < off) sdata[t] += sdata[t + off];
        __syncthreads();
    }
    if (t == 0) bsum[b] = sdata[0];
}

__global__ void k_scan2(int* __restrict__ bsum, int* __restrict__ rowstart) {
    if (threadIdx.x == 0 && blockIdx.x == 0) {
        int run = 0;
        for (int i = 0; i < NB; ++i) { int v = bsum[i]; bsum[i] = run; run += v; }
        rowstart[NN] = run;  // == NE
    }
}

__global__ __launch_bounds__(256) void k_scan3(const int* __restrict__ cnt, const int* __restrict__ bsum,
                                               int* __restrict__ rowstart) {
    __shared__ int sdata[256];
    int b = blockIdx.x, t = threadIdx.x;
    int base = b * SCAN_SEG + t * 4;
    int v[4]; int vsum = 0;
    #pragma unroll
    for (int j = 0; j < 4; ++j) { int idx = base + j; v[j] = (idx < NN) ? cnt[idx] : 0; vsum += v[j]; }
    sdata[t] = vsum; __syncthreads();
    int incl = vsum;
    for (int off = 1; off < 256; off <<= 1) {
        int add = (t >= off) ? sdata[t - off] : 0;
        __syncthreads();
        incl += add;
        sdata[t] = incl;
        __syncthreads();
    }
    int run = bsum[b] + (incl - vsum);
    #pragma unroll
    for (int j = 0; j < 4; ++j) {
        int idx = base + j;
        if (idx < NN) { rowstart[idx] = run; run += v[j]; }
    }
}

// ---------------- CSR fill (no atomics): edat[pos] = {src, bits(RAW w)} ----------------

__global__ __launch_bounds__(256) void k_fill(const int4* __restrict__ src4, const int4* __restrict__ dst4,
                                              const float4* __restrict__ w4, const int* __restrict__ rowstart,
                                              const int4* __restrict__ slot4, int2* __restrict__ edat) {
    int i = blockIdx.x * 256 + threadIdx.x;
    if (i < NE / 4) {
        int4 s = src4[i]; int4 d = dst4[i]; float4 wv = w4[i]; int4 sl = slot4[i];
        edat[rowstart[d.x] + sl.x] = make_int2(s.x, __float_as_int(wv.x));
        edat[rowstart[d.y] + sl.y] = make_int2(s.y, __float_as_int(wv.y));
        edat[rowstart[d.z] + sl.z] = make_int2(s.z, __float_as_int(wv.z));
        edat[rowstart[d.w] + sl.w] = make_int2(s.w, __float_as_int(wv.w));
    }
}

// ---------------- deg -> dinv (no atomics): deg = 1 + sum_row(w) ----------------

__global__ __launch_bounds__(256) void k_degdinv(const int* __restrict__ rs, const int2* __restrict__ edat,
                                                 float* __restrict__ dinv) {
    int i = blockIdx.x * 256 + threadIdx.x;
    if (i < NN) {
        float dg = 1.0f;  // self-loop weight
        int p1 = rs[i + 1];
        for (int p = rs[i]; p < p1; ++p) dg += __int_as_float(edat[p].y);
        dinv[i] = (dg > 0.0f) ? (1.0f / sqrtf(fmaxf(dg, 1e-12f))) : 0.0f;
    }
}

// ---------------- GEMM: H = X @ W  (X [NN,128] f32, W [128,128] f32) ----------------
// 128x128 tile, 256 threads (16x16), 8x8 per thread. Only X^T staged in LDS
// (broadcast, conflict-free reads); W read directly from global (64 KB,
// L2-resident, address shared across ty -> broadcast). LDS demand 64 B/cy at
// peak FMA (half of LDS ceiling) vs 192 B/cy for the old 64x128 tile.

#define GEMM_ROW(ACCP, XS)                                                             \
    do {                                                                               \
        (ACCP)[0].x = fmaf((XS), wv0.x, (ACCP)[0].x);                                  \
        (ACCP)[0].y = fmaf((XS), wv0.y, (ACCP)[0].y);                                  \
        (ACCP)[0].z = fmaf((XS), wv0.z, (ACCP)[0].z);                                  \
        (ACCP)[0].w = fmaf((XS), wv0.w, (ACCP)[0].w);                                  \
        (ACCP)[1].x = fmaf((XS), wv1.x, (ACCP)[1].x);                                  \
        (ACCP)[1].y = fmaf((XS), wv1.y, (ACCP)[1].y);                                  \
        (ACCP)[1].z = fmaf((XS), wv1.z, (ACCP)[1].z);                                  \
        (ACCP)[1].w = fmaf((XS), wv1.w, (ACCP)[1].w);                                  \
    } while (0)

__global__ __launch_bounds__(256) void k_gemm(const float* __restrict__ Xg, const float* __restrict__ Wg,
                                              float* __restrict__ Hg) {
    __shared__ float XsT[32][128];  // 16 KB: [k][row], transposed

    int t  = threadIdx.x;
    int tx = t & 15;       // col group: cols tx*8 .. tx*8+7
    int ty = t >> 4;       // row group: rows ty*8 .. ty*8+7
    int rowBase = blockIdx.x * 128;

    float4 acc[8][2];
    #pragma unroll
    for (int i = 0; i < 8; ++i) { acc[i][0] = make_float4(0.f,0.f,0.f,0.f); acc[i][1] = acc[i][0]; }

    int lr   = t >> 1;            // load row 0..127
    int koff = (t & 1) * 16;      // k offset 0 or 16
    int gr = rowBase + lr; if (gr > NN - 1) gr = NN - 1;
    const float* xp = Xg + (size_t)gr * NC + koff;

    for (int kc = 0; kc < 128; kc += 32) {
        float4 a = *(const float4*)(xp + kc + 0);
        float4 b = *(const float4*)(xp + kc + 4);
        float4 c = *(const float4*)(xp + kc + 8);
        float4 d = *(const float4*)(xp + kc + 12);
        __syncthreads();   // protect previous iteration's reads
        XsT[koff + 0][lr] = a.x;  XsT[koff + 1][lr] = a.y;  XsT[koff + 2][lr] = a.z;  XsT[koff + 3][lr] = a.w;
        XsT[koff + 4][lr] = b.x;  XsT[koff + 5][lr] = b.y;  XsT[koff + 6][lr] = b.z;  XsT[koff + 7][lr] = b.w;
        XsT[koff + 8][lr] = c.x;  XsT[koff + 9][lr] = c.y;  XsT[koff +10][lr] = c.z;  XsT[koff +11][lr] = c.w;
        XsT[koff +12][lr] = d.x;  XsT[koff +13][lr] = d.y;  XsT[koff +14][lr] = d.z;  XsT[koff +15][lr] = d.w;
        __syncthreads();

        const float* wp = Wg + (size_t)kc * NC + tx * 8;
        #pragma unroll 4
        for (int k = 0; k < 32; ++k) {
            float4 wv0 = *(const float4*)(wp + k * NC);
            float4 wv1 = *(const float4*)(wp + k * NC + 4);
            float4 x0 = *(const float4*)&XsT[k][ty * 8];
            float4 x1 = *(const float4*)&XsT[k][ty * 8 + 4];
            GEMM_ROW(acc[0], x0.x);
            GEMM_ROW(acc[1], x0.y);
            GEMM_ROW(acc[2], x0.z);
            GEMM_ROW(acc[3], x0.w);
            GEMM_ROW(acc[4], x1.x);
            GEMM_ROW(acc[5], x1.y);
            GEMM_ROW(acc[6], x1.z);
            GEMM_ROW(acc[7], x1.w);
        }
    }

    #pragma unroll
    for (int i = 0; i < 8; ++i) {
        int grow = rowBase + ty * 8 + i;
        if (grow < NN) {
            *(float4*)&Hg[(size_t)grow * NC + tx * 8]     = acc[i][0];
            *(float4*)&Hg[(size_t)grow * NC + tx * 8 + 4] = acc[i][1];
        }
    }
}

// ---------------- aggregation ----------------
// One 64-lane wave per node. 4 edge-groups x 16 lanes; each lane owns 8 channels
// (2x float4). nw = dinv[src]*w computed in-flight (dinv table L2-resident,
// broadcast across the group); dinv[dst] applied in the epilogue.
// out[d] = dinv[d]*(sum_e dinv[s]*w*H[s] + dinv[d]*H[d]) + b

template <int RELU>
__global__ __launch_bounds__(256) void k_agg(const float* __restrict__ H, const int* __restrict__ rs,
                                             const int2* __restrict__ edat,
                                             const float* __restrict__ dinv, const float* __restrict__ bias,
                                             float* __restrict__ out) {
    int wid  = (blockIdx.x * 256 + threadIdx.x) >> 6;
    int lane = threadIdx.x & 63;
    if (wid >= NN) return;
    int node = wid;
    int g  = lane >> 4;   // edge group 0..3
    int cl = lane & 15;   // channel lane: owns channels cl*8 .. cl*8+7

    float di = dinv[node];
    float4 acc0 = make_float4(0.f, 0.f, 0.f, 0.f);
    float4 acc1 = make_float4(0.f, 0.f, 0.f, 0.f);

    // self-loop contribution (before the final *di): di * H[node]
    if (g == 0) {
        const float4* hp = (const float4*)(H + (size_t)node * NC + cl * 8);
        float4 a = hp[0], b = hp[1];
        acc0.x = a.x * di; acc0.y = a.y * di; acc0.z = a.z * di; acc0.w = a.w * di;
        acc1.x = b.x * di; acc1.y = b.y * di; acc1.z = b.z * di; acc1.w = b.w * di;
    }

    int p0 = rs[node], p1 = rs[node + 1];
    for (int p = p0 + g; p < p1; p += 4) {
        long long r1 = __builtin_nontemporal_load((const long long*)&edat[p]);
        int   s1 = (int)(r1 & 0xffffffffLL);
        float w1 = __int_as_float((int)(r1 >> 32));
        float nw = dinv[s1] * w1;
        const float4* hp = (const float4*)(H + (size_t)s1 * NC + cl * 8);
        float4 a = hp[0], b = hp[1];
        acc0.x = fmaf(nw, a.x, acc0.x); acc0.y = fmaf(nw, a.y, acc0.y);
        acc0.z = fmaf(nw, a.z, acc0.z); acc0.w = fmaf(nw, a.w, acc0.w);
        acc1.x = fmaf(nw, b.x, acc1.x); acc1.y = fmaf(nw, b.y, acc1.y);
        acc1.z = fmaf(nw, b.z, acc1.z); acc1.w = fmaf(nw, b.w, acc1.w);
    }

    // combine the 4 edge-groups: sum over lanes {cl, cl+16, cl+32, cl+48}
    #pragma unroll
    for (int m = 16; m <= 32; m <<= 1) {
        acc0.x += __shfl_xor(acc0.x, m); acc0.y += __shfl_xor(acc0.y, m);
        acc0.z += __shfl_xor(acc0.z, m); acc0.w += __shfl_xor(acc0.w, m);
        acc1.x += __shfl_xor(acc1.x, m); acc1.y += __shfl_xor(acc1.y, m);
        acc1.z += __shfl_xor(acc1.z, m); acc1.w += __shfl_xor(acc1.w, m);
    }

    if (g == 0) {
        const float4* bp = (const float4*)(bias + cl * 8);
        float4 bv0 = bp[0], bv1 = bp[1];
        acc0.x = fmaf(acc0.x, di, bv0.x); acc0.y = fmaf(acc0.y, di, bv0.y);
        acc0.z = fmaf(acc0.z, di, bv0.z); acc0.w = fmaf(acc0.w, di, bv0.w);
        acc1.x = fmaf(acc1.x, di, bv1.x); acc1.y = fmaf(acc1.y, di, bv1.y);
        acc1.z = fmaf(acc1.z, di, bv1.z); acc1.w = fmaf(acc1.w, di, bv1.w);
        if (RELU) {
            acc0.x = fmaxf(acc0.x, 0.f); acc0.y = fmaxf(acc0.y, 0.f);
            acc0.z = fmaxf(acc0.z, 0.f); acc0.w = fmaxf(acc0.w, 0.f);
            acc1.x = fmaxf(acc1.x, 0.f); acc1.y = fmaxf(acc1.y, 0.f);
            acc1.z = fmaxf(acc1.z, 0.f); acc1.w = fmaxf(acc1.w, 0.f);
        }
        float4* op = (float4*)(out + (size_t)node * NC + cl * 8);
        op[0] = acc0;
        op[1] = acc1;
    }
}

// ---------------- launch ----------------

static inline size_t alignup(size_t x) { return (x + 255) & ~(size_t)255; }

extern "C" void kernel_launch(void* const* d_in, const int* in_sizes, int n_in,
                              void* d_out, int out_size, void* d_ws, size_t ws_size,
                              hipStream_t stream) {
    const float* X  = (const float*)d_in[0];
    const int*   ei = (const int*)d_in[1];          // [2, NE]: row0 = src, row1 = dst
    const float* ew = (const float*)d_in[2];
    const float* W1 = (const float*)d_in[3]; const float* b1 = (const float*)d_in[4];
    const float* W2 = (const float*)d_in[5]; const float* b2 = (const float*)d_in[6];
    const float* W3 = (const float*)d_in[7]; const float* b3 = (const float*)d_in[8];
    float* out = (float*)d_out;

    const int* srcp = ei;
    const int* dstp = ei + NE;

    // workspace carve
    char* w = (char*)d_ws;
    size_t need = 0;
    auto carve = [&](size_t bytes) { char* p = w + need; need += alignup(bytes); return p; };
    float* dinv     = (float*)carve(NN * 4);
    int*   cnt      = (int*)  carve(NN * 4);
    int*   rowstart = (int*)  carve((NN + 1) * 4);
    int*   bsum     = (int*)  carve(NB * 4);
    int*   slot     = (int*)  carve((size_t)NE * 4);
    int2*  edat     = (int2*) carve((size_t)NE * 8);
    float* H        = (float*)carve((size_t)NN * NC * 4);
    float* A        = (float*)carve((size_t)NN * NC * 4);
    if (need > ws_size) return;  // workspace too small -> visible validation failure

    const int gN  = (NN + 255) / 256;
    const int gE4 = (NE / 4 + 255) / 256;
    const int gGemm = (NN + 127) / 128;
    const int gAgg  = (NN * 64 + 255) / 256;  // one wave per node

    // build normalization + CSR (once; reused by all 3 layers)
    k_init<<<gN, 256, 0, stream>>>(cnt);
    k_count<<<gE4, 256, 0, stream>>>((const int4*)dstp, cnt, (int4*)slot);
    k_scan1<<<NB, 256, 0, stream>>>(cnt, bsum);
    k_scan2<<<1, 64, 0, stream>>>(bsum, rowstart);
    k_scan3<<<NB, 256, 0, stream>>>(cnt, bsum, rowstart);
    k_fill<<<gE4, 256, 0, stream>>>((const int4*)srcp, (const int4*)dstp, (const float4*)ew,
                                    rowstart, (const int4*)slot, edat);
    k_degdinv<<<gN, 256, 0, stream>>>(rowstart, edat, dinv);

    // layer 1
    k_gemm<<<gGemm, 256, 0, stream>>>(X, W1, H);
    k_agg<1><<<gAgg, 256, 0, stream>>>(H, rowstart, edat, dinv, b1, A);
    // layer 2
    k_gemm<<<gGemm, 256, 0, stream>>>(A, W2, H);
    k_agg<1><<<gAgg, 256, 0, stream>>>(H, rowstart, edat, dinv, b2, A);
    // layer 3
    k_gemm<<<gGemm, 256, 0, stream>>>(A, W3, H);
    k_agg<0><<<gAgg, 256, 0, stream>>>(H, rowstart, edat, dinv, b3, out);
}

// Round 6
// 550.266 us; speedup vs baseline: 1.2474x; 1.2474x over previous
//
#include <hip/hip_runtime.h>
#include <hip/hip_bf16.h>
#include <cstdint>

#define NN 100000
#define NE 1600000
#define NC 128

constexpr int SCAN_SEG = 1024;
constexpr int NB = (NN + SCAN_SEG - 1) / SCAN_SEG; // 98

// ---------------- CSR build ----------------

__global__ __launch_bounds__(256) void k_init(int* __restrict__ cnt) {
    int i = blockIdx.x * 256 + threadIdx.x;
    if (i < NN) cnt[i] = 0;
}

// one int atomic per edge; returned old value = within-row slot. 4 edges/thread.
__global__ __launch_bounds__(256) void k_count(const int4* __restrict__ dst4, int* __restrict__ cnt,
                                               int4* __restrict__ slot4) {
    int i = blockIdx.x * 256 + threadIdx.x;
    if (i < NE / 4) {
        int4 d = dst4[i];
        int4 s;
        s.x = atomicAdd(&cnt[d.x], 1);
        s.y = atomicAdd(&cnt[d.y], 1);
        s.z = atomicAdd(&cnt[d.z], 1);
        s.w = atomicAdd(&cnt[d.w], 1);
        slot4[i] = s;
    }
}

// ---------------- exclusive scan of cnt -> rowstart ----------------

__global__ __launch_bounds__(256) void k_scan1(const int* __restrict__ cnt, int* __restrict__ bsum) {
    __shared__ int sdata[256];
    int b = blockIdx.x, t = threadIdx.x;
    int base = b * SCAN_SEG + t * 4;
    int s = 0;
    #pragma unroll
    for (int j = 0; j < 4; ++j) { int idx = base + j; if (idx < NN) s += cnt[idx]; }
    sdata[t] = s; __syncthreads();
    for (int off = 128; off > 0; off >>= 1) {
        if (t < off) sdata[t] += sdata[t + off];
        __syncthreads();
    }
    if (t == 0) bsum[b] = sdata[0];
}

__global__ void k_scan2(int* __restrict__ bsum, int* __restrict__ rowstart) {
    if (threadIdx.x == 0 && blockIdx.x == 0) {
        int run = 0;
        for (int i = 0; i < NB; ++i) { int v = bsum[i]; bsum[i] = run; run += v; }
        rowstart[NN] = run;  // == NE
    }
}

__global__ __launch_bounds__(256) void k_scan3(const int* __restrict__ cnt, const int* __restrict__ bsum,
                                               int* __restrict__ rowstart) {
    __shared__ int sdata[256];
    int b = blockIdx.x, t = threadIdx.x;
    int base = b * SCAN_SEG + t * 4;
    int v[4]; int vsum = 0;
    #pragma unroll
    for (int j = 0; j < 4; ++j) { int idx = base + j; v[j] = (idx < NN) ? cnt[idx] : 0; vsum += v[j]; }
    sdata[t] = vsum; __syncthreads();
    int incl = vsum;
    for (int off = 1; off < 256; off <<= 1) {
        int add = (t >= off) ? sdata[t - off] : 0;
        __syncthreads();
        incl += add;
        sdata[t] = incl;
        __syncthreads();
    }
    int run = bsum[b] + (incl - vsum);
    #pragma unroll
    for (int j = 0; j < 4; ++j) {
        int idx = base + j;
        if (idx < NN) { rowstart[idx] = run; run += v[j]; }
    }
}

// ---------------- CSR fill (no atomics): edat[pos] = {src, bits(RAW w)} ----------------

__global__ __launch_bounds__(256) void k_fill(const int4* __restrict__ src4, const int4* __restrict__ dst4,
                                              const float4* __restrict__ w4, const int* __restrict__ rowstart,
                                              const int4* __restrict__ slot4, int2* __restrict__ edat) {
    int i = blockIdx.x * 256 + threadIdx.x;
    if (i < NE / 4) {
        int4 s = src4[i]; int4 d = dst4[i]; float4 wv = w4[i]; int4 sl = slot4[i];
        edat[rowstart[d.x] + sl.x] = make_int2(s.x, __float_as_int(wv.x));
        edat[rowstart[d.y] + sl.y] = make_int2(s.y, __float_as_int(wv.y));
        edat[rowstart[d.z] + sl.z] = make_int2(s.z, __float_as_int(wv.z));
        edat[rowstart[d.w] + sl.w] = make_int2(s.w, __float_as_int(wv.w));
    }
}

// ---------------- deg -> dinv (no atomics): deg = 1 + sum_row(w) ----------------

__global__ __launch_bounds__(256) void k_degdinv(const int* __restrict__ rs, const int2* __restrict__ edat,
                                                 float* __restrict__ dinv) {
    int i = blockIdx.x * 256 + threadIdx.x;
    if (i < NN) {
        float dg = 1.0f;  // self-loop weight
        int p1 = rs[i + 1];
        for (int p = rs[i]; p < p1; ++p) dg += __int_as_float(edat[p].y);
        dinv[i] = (dg > 0.0f) ? (1.0f / sqrtf(fmaxf(dg, 1e-12f))) : 0.0f;
    }
}

// ---------------- norm: edat[p].y = bits(dinv[src] * w)  (dinv[dst] applied in k_agg) ----------------

__global__ __launch_bounds__(256) void k_norm(const float* __restrict__ dinv, int2* __restrict__ edat) {
    int p = blockIdx.x * 256 + threadIdx.x;
    if (p < NE) {
        int2 ed = edat[p];
        edat[p].y = __float_as_int(dinv[ed.x] * __int_as_float(ed.y));
    }
}

// ---------------- bf16 helpers ----------------

__device__ __forceinline__ unsigned short f2bf(float f) {
    unsigned int u = __float_as_uint(f);
    u = (u + 0x7fffu + ((u >> 16) & 1u)) >> 16;   // RNE
    return (unsigned short)u;
}
#define BFLO(u) __uint_as_float((u) << 16)
#define BFHI(u) __uint_as_float((u) & 0xffff0000u)

// ---------------- GEMM: Hb = bf16(X @ W)  (X [NN,128] f32, W [128,128] f32) ----------------
// block 256 = 8 row-threads x 32 col-threads; tile 64 rows x 128 cols; thread 8 rows x 4 cols.

__global__ __launch_bounds__(256) void k_gemm(const float* __restrict__ Xg, const float* __restrict__ Wg,
                                              unsigned short* __restrict__ Hb) {
    __shared__ float Ws[64][128];  // 32 KB
    __shared__ float Xs[64][64];   // 16 KB

    int t  = threadIdx.x;
    int tx = t & 31;
    int ty = t >> 5;
    int c0 = tx * 4;
    int rowBase = blockIdx.x * 64;

    float4 acc[8];
    #pragma unroll
    for (int r = 0; r < 8; ++r) acc[r] = make_float4(0.f, 0.f, 0.f, 0.f);

    for (int kc = 0; kc < 128; kc += 64) {
        #pragma unroll
        for (int j = 0; j < 8; ++j) {
            int l  = (t + j * 256) * 4;
            int kr = l >> 7;
            int cc = l & 127;
            *(float4*)&Ws[kr][cc] = *(const float4*)&Wg[(kc + kr) * NC + cc];
        }
        #pragma unroll
        for (int j = 0; j < 4; ++j) {
            int l  = (t + j * 256) * 4;
            int rr = l >> 6;
            int kk = l & 63;
            int gr = rowBase + rr; if (gr > NN - 1) gr = NN - 1;
            *(float4*)&Xs[rr][kk] = *(const float4*)&Xg[(size_t)gr * NC + kc + kk];
        }
        __syncthreads();

        #pragma unroll 4
        for (int kk = 0; kk < 64; kk += 4) {
            float4 wv0 = *(const float4*)&Ws[kk + 0][c0];
            float4 wv1 = *(const float4*)&Ws[kk + 1][c0];
            float4 wv2 = *(const float4*)&Ws[kk + 2][c0];
            float4 wv3 = *(const float4*)&Ws[kk + 3][c0];
            #pragma unroll
            for (int r = 0; r < 8; ++r) {
                float4 xv = *(const float4*)&Xs[ty * 8 + r][kk];
                acc[r].x = fmaf(xv.x, wv0.x, acc[r].x); acc[r].y = fmaf(xv.x, wv0.y, acc[r].y);
                acc[r].z = fmaf(xv.x, wv0.z, acc[r].z); acc[r].w = fmaf(xv.x, wv0.w, acc[r].w);
                acc[r].x = fmaf(xv.y, wv1.x, acc[r].x); acc[r].y = fmaf(xv.y, wv1.y, acc[r].y);
                acc[r].z = fmaf(xv.y, wv1.z, acc[r].z); acc[r].w = fmaf(xv.y, wv1.w, acc[r].w);
                acc[r].x = fmaf(xv.z, wv2.x, acc[r].x); acc[r].y = fmaf(xv.z, wv2.y, acc[r].y);
                acc[r].z = fmaf(xv.z, wv2.z, acc[r].z); acc[r].w = fmaf(xv.z, wv2.w, acc[r].w);
                acc[r].x = fmaf(xv.w, wv3.x, acc[r].x); acc[r].y = fmaf(xv.w, wv3.y, acc[r].y);
                acc[r].z = fmaf(xv.w, wv3.z, acc[r].z); acc[r].w = fmaf(xv.w, wv3.w, acc[r].w);
            }
        }
        __syncthreads();
    }

    #pragma unroll
    for (int r = 0; r < 8; ++r) {
        int gr = rowBase + ty * 8 + r;
        if (gr < NN) {
            ushort4 o;
            o.x = f2bf(acc[r].x); o.y = f2bf(acc[r].y);
            o.z = f2bf(acc[r].z); o.w = f2bf(acc[r].w);
            *(ushort4*)&Hb[(size_t)gr * NC + c0] = o;
        }
    }
}

// ---------------- aggregation ----------------
// One 64-lane wave per node. 4 edge-groups x 16 lanes; each lane owns 8 channels.
// Hb is bf16: one dwordx4 (16 B = 8 channels) per lane per edge, unpacked via
// shift/and. out[d] = dinv[d]*(sum_e nrm'*Hb[s] + dinv[d]*Hb[d]) + b, f32 accum.

template <int RELU>
__global__ __launch_bounds__(256) void k_agg(const unsigned short* __restrict__ Hb, const int* __restrict__ rs,
                                             const int2* __restrict__ edat,
                                             const float* __restrict__ dinv, const float* __restrict__ bias,
                                             float* __restrict__ out) {
    int wid  = (blockIdx.x * 256 + threadIdx.x) >> 6;
    int lane = threadIdx.x & 63;
    if (wid >= NN) return;
    int node = wid;
    int g  = lane >> 4;   // edge group 0..3
    int cl = lane & 15;   // channel lane: owns channels cl*8 .. cl*8+7

    float di = dinv[node];
    float4 acc0 = make_float4(0.f, 0.f, 0.f, 0.f);
    float4 acc1 = make_float4(0.f, 0.f, 0.f, 0.f);

    // self-loop contribution (before the final *di): di * H[node]
    if (g == 0) {
        uint4 U = *(const uint4*)(Hb + (size_t)node * NC + cl * 8);
        acc0.x = BFLO(U.x) * di; acc0.y = BFHI(U.x) * di;
        acc0.z = BFLO(U.y) * di; acc0.w = BFHI(U.y) * di;
        acc1.x = BFLO(U.z) * di; acc1.y = BFHI(U.z) * di;
        acc1.z = BFLO(U.w) * di; acc1.w = BFHI(U.w) * di;
    }

    int p0 = rs[node], p1 = rs[node + 1];
    for (int p = p0 + g; p < p1; p += 4) {
        long long r1 = __builtin_nontemporal_load((const long long*)&edat[p]);
        int   s1 = (int)(r1 & 0xffffffffLL);
        float nw = __int_as_float((int)(r1 >> 32));
        uint4 U = *(const uint4*)(Hb + (size_t)s1 * NC + cl * 8);
        acc0.x = fmaf(nw, BFLO(U.x), acc0.x); acc0.y = fmaf(nw, BFHI(U.x), acc0.y);
        acc0.z = fmaf(nw, BFLO(U.y), acc0.z); acc0.w = fmaf(nw, BFHI(U.y), acc0.w);
        acc1.x = fmaf(nw, BFLO(U.z), acc1.x); acc1.y = fmaf(nw, BFHI(U.z), acc1.y);
        acc1.z = fmaf(nw, BFLO(U.w), acc1.z); acc1.w = fmaf(nw, BFHI(U.w), acc1.w);
    }

    // combine the 4 edge-groups: sum over lanes {cl, cl+16, cl+32, cl+48}
    #pragma unroll
    for (int m = 16; m <= 32; m <<= 1) {
        acc0.x += __shfl_xor(acc0.x, m); acc0.y += __shfl_xor(acc0.y, m);
        acc0.z += __shfl_xor(acc0.z, m); acc0.w += __shfl_xor(acc0.w, m);
        acc1.x += __shfl_xor(acc1.x, m); acc1.y += __shfl_xor(acc1.y, m);
        acc1.z += __shfl_xor(acc1.z, m); acc1.w += __shfl_xor(acc1.w, m);
    }

    if (g == 0) {
        const float4* bp = (const float4*)(bias + cl * 8);
        float4 bv0 = bp[0], bv1 = bp[1];
        acc0.x = fmaf(acc0.x, di, bv0.x); acc0.y = fmaf(acc0.y, di, bv0.y);
        acc0.z = fmaf(acc0.z, di, bv0.z); acc0.w = fmaf(acc0.w, di, bv0.w);
        acc1.x = fmaf(acc1.x, di, bv1.x); acc1.y = fmaf(acc1.y, di, bv1.y);
        acc1.z = fmaf(acc1.z, di, bv1.z); acc1.w = fmaf(acc1.w, di, bv1.w);
        if (RELU) {
            acc0.x = fmaxf(acc0.x, 0.f); acc0.y = fmaxf(acc0.y, 0.f);
            acc0.z = fmaxf(acc0.z, 0.f); acc0.w = fmaxf(acc0.w, 0.f);
            acc1.x = fmaxf(acc1.x, 0.f); acc1.y = fmaxf(acc1.y, 0.f);
            acc1.z = fmaxf(acc1.z, 0.f); acc1.w = fmaxf(acc1.w, 0.f);
        }
        float4* op = (float4*)(out + (size_t)node * NC + cl * 8);
        op[0] = acc0;
        op[1] = acc1;
    }
}

// ---------------- launch ----------------

static inline size_t alignup(size_t x) { return (x + 255) & ~(size_t)255; }

extern "C" void kernel_launch(void* const* d_in, const int* in_sizes, int n_in,
                              void* d_out, int out_size, void* d_ws, size_t ws_size,
                              hipStream_t stream) {
    const float* X  = (const float*)d_in[0];
    const int*   ei = (const int*)d_in[1];          // [2, NE]: row0 = src, row1 = dst
    const float* ew = (const float*)d_in[2];
    const float* W1 = (const float*)d_in[3]; const float* b1 = (const float*)d_in[4];
    const float* W2 = (const float*)d_in[5]; const float* b2 = (const float*)d_in[6];
    const float* W3 = (const float*)d_in[7]; const float* b3 = (const float*)d_in[8];
    float* out = (float*)d_out;

    const int* srcp = ei;
    const int* dstp = ei + NE;

    // workspace carve
    char* w = (char*)d_ws;
    size_t need = 0;
    auto carve = [&](size_t bytes) { char* p = w + need; need += alignup(bytes); return p; };
    float* dinv     = (float*)carve(NN * 4);
    int*   cnt      = (int*)  carve(NN * 4);
    int*   rowstart = (int*)  carve((NN + 1) * 4);
    int*   bsum     = (int*)  carve(NB * 4);
    int*   slot     = (int*)  carve((size_t)NE * 4);
    int2*  edat     = (int2*) carve((size_t)NE * 8);
    unsigned short* Hb = (unsigned short*)carve((size_t)NN * NC * 2);
    float* A        = (float*)carve((size_t)NN * NC * 4);
    if (need > ws_size) return;  // workspace too small -> visible validation failure

    const int gN  = (NN + 255) / 256;
    const int gE  = (NE + 255) / 256;
    const int gE4 = (NE / 4 + 255) / 256;
    const int gGemm = (NN + 63) / 64;
    const int gAgg  = (NN * 64 + 255) / 256;  // one wave per node

    // build normalization + CSR (once; reused by all 3 layers)
    k_init<<<gN, 256, 0, stream>>>(cnt);
    k_count<<<gE4, 256, 0, stream>>>((const int4*)dstp, cnt, (int4*)slot);
    k_scan1<<<NB, 256, 0, stream>>>(cnt, bsum);
    k_scan2<<<1, 64, 0, stream>>>(bsum, rowstart);
    k_scan3<<<NB, 256, 0, stream>>>(cnt, bsum, rowstart);
    k_fill<<<gE4, 256, 0, stream>>>((const int4*)srcp, (const int4*)dstp, (const float4*)ew,
                                    rowstart, (const int4*)slot, edat);
    k_degdinv<<<gN, 256, 0, stream>>>(rowstart, edat, dinv);
    k_norm<<<gE, 256, 0, stream>>>(dinv, edat);

    // layer 1
    k_gemm<<<gGemm, 256, 0, stream>>>(X, W1, Hb);
    k_agg<1><<<gAgg, 256, 0, stream>>>(Hb, rowstart, edat, dinv, b1, A);
    // layer 2
    k_gemm<<<gGemm, 256, 0, stream>>>(A, W2, Hb);
    k_agg<1><<<gAgg, 256, 0, stream>>>(Hb, rowstart, edat, dinv, b2, A);
    // layer 3
    k_gemm<<<gGemm, 256, 0, stream>>>(A, W3, Hb);
    k_agg<0><<<gAgg, 256, 0, stream>>>(Hb, rowstart, edat, dinv, b3, out);
}

// Round 7
// 519.263 us; speedup vs baseline: 1.3219x; 1.0597x over previous
//
#include <hip/hip_runtime.h>
#include <hip/hip_bf16.h>
#include <cstdint>

#define NN 100000
#define NE 1600000
#define NC 128

constexpr int SCAN_SEG = 1024;
constexpr int NB = (NN + SCAN_SEG - 1) / SCAN_SEG; // 98

// ---------------- CSR build ----------------

__global__ __launch_bounds__(256) void k_init(int* __restrict__ cnt) {
    int i = blockIdx.x * 256 + threadIdx.x;
    if (i < NN) cnt[i] = 0;
}

// one int atomic per edge; returned old value = within-row slot. 4 edges/thread.
__global__ __launch_bounds__(256) void k_count(const int4* __restrict__ dst4, int* __restrict__ cnt,
                                               int4* __restrict__ slot4) {
    int i = blockIdx.x * 256 + threadIdx.x;
    if (i < NE / 4) {
        int4 d = dst4[i];
        int4 s;
        s.x = atomicAdd(&cnt[d.x], 1);
        s.y = atomicAdd(&cnt[d.y], 1);
        s.z = atomicAdd(&cnt[d.z], 1);
        s.w = atomicAdd(&cnt[d.w], 1);
        slot4[i] = s;
    }
}

// ---------------- exclusive scan of cnt -> rowstart ----------------

__global__ __launch_bounds__(256) void k_scan1(const int* __restrict__ cnt, int* __restrict__ bsum) {
    __shared__ int sdata[256];
    int b = blockIdx.x, t = threadIdx.x;
    int base = b * SCAN_SEG + t * 4;
    int s = 0;
    #pragma unroll
    for (int j = 0; j < 4; ++j) { int idx = base + j; if (idx < NN) s += cnt[idx]; }
    sdata[t] = s; __syncthreads();
    for (int off = 128; off > 0; off >>= 1) {
        if (t < off) sdata[t] += sdata[t + off];
        __syncthreads();
    }
    if (t == 0) bsum[b] = sdata[0];
}

__global__ void k_scan2(int* __restrict__ bsum, int* __restrict__ rowstart) {
    if (threadIdx.x == 0 && blockIdx.x == 0) {
        int run = 0;
        for (int i = 0; i < NB; ++i) { int v = bsum[i]; bsum[i] = run; run += v; }
        rowstart[NN] = run;  // == NE
    }
}

__global__ __launch_bounds__(256) void k_scan3(const int* __restrict__ cnt, const int* __restrict__ bsum,
                                               int* __restrict__ rowstart) {
    __shared__ int sdata[256];
    int b = blockIdx.x, t = threadIdx.x;
    int base = b * SCAN_SEG + t * 4;
    int v[4]; int vsum = 0;
    #pragma unroll
    for (int j = 0; j < 4; ++j) { int idx = base + j; v[j] = (idx < NN) ? cnt[idx] : 0; vsum += v[j]; }
    sdata[t] = vsum; __syncthreads();
    int incl = vsum;
    for (int off = 1; off < 256; off <<= 1) {
        int add = (t >= off) ? sdata[t - off] : 0;
        __syncthreads();
        incl += add;
        sdata[t] = incl;
        __syncthreads();
    }
    int run = bsum[b] + (incl - vsum);
    #pragma unroll
    for (int j = 0; j < 4; ++j) {
        int idx = base + j;
        if (idx < NN) { rowstart[idx] = run; run += v[j]; }
    }
}

// ---------------- CSR fill (no atomics): edat[pos] = {src, bits(RAW w)} ----------------

__global__ __launch_bounds__(256) void k_fill(const int4* __restrict__ src4, const int4* __restrict__ dst4,
                                              const float4* __restrict__ w4, const int* __restrict__ rowstart,
                                              const int4* __restrict__ slot4, int2* __restrict__ edat) {
    int i = blockIdx.x * 256 + threadIdx.x;
    if (i < NE / 4) {
        int4 s = src4[i]; int4 d = dst4[i]; float4 wv = w4[i]; int4 sl = slot4[i];
        edat[rowstart[d.x] + sl.x] = make_int2(s.x, __float_as_int(wv.x));
        edat[rowstart[d.y] + sl.y] = make_int2(s.y, __float_as_int(wv.y));
        edat[rowstart[d.z] + sl.z] = make_int2(s.z, __float_as_int(wv.z));
        edat[rowstart[d.w] + sl.w] = make_int2(s.w, __float_as_int(wv.w));
    }
}

// ---------------- deg -> dinv (no atomics): deg = 1 + sum_row(w) ----------------

__global__ __launch_bounds__(256) void k_degdinv(const int* __restrict__ rs, const int2* __restrict__ edat,
                                                 float* __restrict__ dinv) {
    int i = blockIdx.x * 256 + threadIdx.x;
    if (i < NN) {
        float dg = 1.0f;  // self-loop weight
        int p1 = rs[i + 1];
        for (int p = rs[i]; p < p1; ++p) dg += __int_as_float(edat[p].y);
        dinv[i] = (dg > 0.0f) ? (1.0f / sqrtf(fmaxf(dg, 1e-12f))) : 0.0f;
    }
}

// ---------------- norm: edat[p].y = bits(dinv[src] * w)  (dinv[dst] applied in k_agg) ----------------

__global__ __launch_bounds__(256) void k_norm(const float* __restrict__ dinv, int2* __restrict__ edat) {
    int p = blockIdx.x * 256 + threadIdx.x;
    if (p < NE) {
        int2 ed = edat[p];
        edat[p].y = __float_as_int(dinv[ed.x] * __int_as_float(ed.y));
    }
}

// ---------------- bf16 helpers ----------------

__device__ __forceinline__ unsigned short f2bf(float f) {
    unsigned int u = __float_as_uint(f);
    u = (u + 0x7fffu + ((u >> 16) & 1u)) >> 16;   // RNE
    return (unsigned short)u;
}
#define BFLO(u) __uint_as_float((u) << 16)
#define BFHI(u) __uint_as_float((u) & 0xffff0000u)

// ---------------- GEMM: Hb = bf16(X @ W) ----------------
// 128x128 tile, 256 threads (16x16), 8 rows x 8 cols per thread.
// Both operands staged in LDS (32 KB, kc=32). Thread's cols = {tx*4..+3,
// 64+tx*4..+3} -> W LDS reads are 2-way bank aliases (free per m136); Xs
// stored transposed [k][row] -> conflict-free. Per k per wave: 4
// ds_read_b128 (~48 cyc) vs 64 v_fma (128 cyc) -> VALU-bound.

__global__ __launch_bounds__(256) void k_gemm(const float* __restrict__ Xg, const float* __restrict__ Wg,
                                              unsigned short* __restrict__ Hb) {
    __shared__ float Xs[32][128];  // [k][row] 16 KB
    __shared__ float Ws[32][128];  // [k][col] 16 KB

    int t  = threadIdx.x;
    int tx = t & 15;       // col group: cols tx*4..+3 and 64+tx*4..+3
    int ty = t >> 4;       // row group: rows ty*8..+7
    int rowBase = blockIdx.x * 128;

    float4 accA[8], accB[8];
    #pragma unroll
    for (int r = 0; r < 8; ++r) { accA[r] = make_float4(0.f,0.f,0.f,0.f); accB[r] = accA[r]; }

    int lrow = t & 127;           // staging row
    int lq   = t >> 7;            // k-half 0/1
    int gr = rowBase + lrow; if (gr > NN - 1) gr = NN - 1;
    const float* xp = Xg + (size_t)gr * NC + lq * 16;

    for (int kc = 0; kc < 128; kc += 32) {
        float4 xa = *(const float4*)(xp + kc + 0);
        float4 xb = *(const float4*)(xp + kc + 4);
        float4 xc = *(const float4*)(xp + kc + 8);
        float4 xd = *(const float4*)(xp + kc + 12);
        float4 wl[4];
        #pragma unroll
        for (int j = 0; j < 4; ++j) {
            int l = (t + j * 256) * 4;
            wl[j] = *(const float4*)&Wg[(size_t)(kc + (l >> 7)) * NC + (l & 127)];
        }
        __syncthreads();   // previous iteration's LDS reads done
        int kb = lq * 16;
        Xs[kb+ 0][lrow] = xa.x; Xs[kb+ 1][lrow] = xa.y; Xs[kb+ 2][lrow] = xa.z; Xs[kb+ 3][lrow] = xa.w;
        Xs[kb+ 4][lrow] = xb.x; Xs[kb+ 5][lrow] = xb.y; Xs[kb+ 6][lrow] = xb.z; Xs[kb+ 7][lrow] = xb.w;
        Xs[kb+ 8][lrow] = xc.x; Xs[kb+ 9][lrow] = xc.y; Xs[kb+10][lrow] = xc.z; Xs[kb+11][lrow] = xc.w;
        Xs[kb+12][lrow] = xd.x; Xs[kb+13][lrow] = xd.y; Xs[kb+14][lrow] = xd.z; Xs[kb+15][lrow] = xd.w;
        #pragma unroll
        for (int j = 0; j < 4; ++j) {
            int l = (t + j * 256) * 4;
            *(float4*)&Ws[l >> 7][l & 127] = wl[j];
        }
        __syncthreads();

        #pragma unroll 8
        for (int k = 0; k < 32; ++k) {
            float4 wv0 = *(const float4*)&Ws[k][tx * 4];
            float4 wv1 = *(const float4*)&Ws[k][64 + tx * 4];
            float4 xv0 = *(const float4*)&Xs[k][ty * 8];
            float4 xv1 = *(const float4*)&Xs[k][ty * 8 + 4];
            float xs[8] = {xv0.x, xv0.y, xv0.z, xv0.w, xv1.x, xv1.y, xv1.z, xv1.w};
            #pragma unroll
            for (int r = 0; r < 8; ++r) {
                accA[r].x = fmaf(xs[r], wv0.x, accA[r].x);
                accA[r].y = fmaf(xs[r], wv0.y, accA[r].y);
                accA[r].z = fmaf(xs[r], wv0.z, accA[r].z);
                accA[r].w = fmaf(xs[r], wv0.w, accA[r].w);
                accB[r].x = fmaf(xs[r], wv1.x, accB[r].x);
                accB[r].y = fmaf(xs[r], wv1.y, accB[r].y);
                accB[r].z = fmaf(xs[r], wv1.z, accB[r].z);
                accB[r].w = fmaf(xs[r], wv1.w, accB[r].w);
            }
        }
    }

    #pragma unroll
    for (int r = 0; r < 8; ++r) {
        int grow = rowBase + ty * 8 + r;
        if (grow < NN) {
            ushort4 oa, ob;
            oa.x = f2bf(accA[r].x); oa.y = f2bf(accA[r].y); oa.z = f2bf(accA[r].z); oa.w = f2bf(accA[r].w);
            ob.x = f2bf(accB[r].x); ob.y = f2bf(accB[r].y); ob.z = f2bf(accB[r].z); ob.w = f2bf(accB[r].w);
            *(ushort4*)&Hb[(size_t)grow * NC + tx * 4]      = oa;
            *(ushort4*)&Hb[(size_t)grow * NC + 64 + tx * 4] = ob;
        }
    }
}

// ---------------- aggregation ----------------
// One 64-lane wave per node. 4 edge-groups x 16 lanes; each lane owns 8 channels
// (one dwordx4 of bf16 per edge). 2-way unrolled edge walk -> 8 edges in
// flight per wave. out[d] = dinv[d]*(sum_e nrm'*Hb[s] + dinv[d]*Hb[d]) + b.

template <int RELU>
__global__ __launch_bounds__(256) void k_agg(const unsigned short* __restrict__ Hb, const int* __restrict__ rs,
                                             const int2* __restrict__ edat,
                                             const float* __restrict__ dinv, const float* __restrict__ bias,
                                             float* __restrict__ out) {
    int wid  = (blockIdx.x * 256 + threadIdx.x) >> 6;
    int lane = threadIdx.x & 63;
    if (wid >= NN) return;
    int node = wid;
    int g  = lane >> 4;   // edge group 0..3
    int cl = lane & 15;   // channel lane: owns channels cl*8 .. cl*8+7

    float di = dinv[node];
    float4 acc0 = make_float4(0.f, 0.f, 0.f, 0.f);
    float4 acc1 = make_float4(0.f, 0.f, 0.f, 0.f);

    // self-loop contribution (before the final *di): di * H[node]
    if (g == 0) {
        uint4 U = *(const uint4*)(Hb + (size_t)node * NC + cl * 8);
        acc0.x = BFLO(U.x) * di; acc0.y = BFHI(U.x) * di;
        acc0.z = BFLO(U.y) * di; acc0.w = BFHI(U.y) * di;
        acc1.x = BFLO(U.z) * di; acc1.y = BFHI(U.z) * di;
        acc1.z = BFLO(U.w) * di; acc1.w = BFHI(U.w) * di;
    }

    int p0 = rs[node], p1 = rs[node + 1];
    int p = p0 + g;
    for (; p + 4 < p1; p += 8) {
        long long r1 = __builtin_nontemporal_load((const long long*)&edat[p]);
        long long r2 = __builtin_nontemporal_load((const long long*)&edat[p + 4]);
        int   s1 = (int)(r1 & 0xffffffffLL);  float nw1 = __int_as_float((int)(r1 >> 32));
        int   s2 = (int)(r2 & 0xffffffffLL);  float nw2 = __int_as_float((int)(r2 >> 32));
        uint4 U = *(const uint4*)(Hb + (size_t)s1 * NC + cl * 8);
        uint4 V = *(const uint4*)(Hb + (size_t)s2 * NC + cl * 8);
        acc0.x = fmaf(nw1, BFLO(U.x), acc0.x); acc0.y = fmaf(nw1, BFHI(U.x), acc0.y);
        acc0.z = fmaf(nw1, BFLO(U.y), acc0.z); acc0.w = fmaf(nw1, BFHI(U.y), acc0.w);
        acc1.x = fmaf(nw1, BFLO(U.z), acc1.x); acc1.y = fmaf(nw1, BFHI(U.z), acc1.y);
        acc1.z = fmaf(nw1, BFLO(U.w), acc1.z); acc1.w = fmaf(nw1, BFHI(U.w), acc1.w);
        acc0.x = fmaf(nw2, BFLO(V.x), acc0.x); acc0.y = fmaf(nw2, BFHI(V.x), acc0.y);
        acc0.z = fmaf(nw2, BFLO(V.y), acc0.z); acc0.w = fmaf(nw2, BFHI(V.y), acc0.w);
        acc1.x = fmaf(nw2, BFLO(V.z), acc1.x); acc1.y = fmaf(nw2, BFHI(V.z), acc1.y);
        acc1.z = fmaf(nw2, BFLO(V.w), acc1.z); acc1.w = fmaf(nw2, BFHI(V.w), acc1.w);
    }
    if (p < p1) {
        long long r1 = __builtin_nontemporal_load((const long long*)&edat[p]);
        int   s1 = (int)(r1 & 0xffffffffLL);  float nw1 = __int_as_float((int)(r1 >> 32));
        uint4 U = *(const uint4*)(Hb + (size_t)s1 * NC + cl * 8);
        acc0.x = fmaf(nw1, BFLO(U.x), acc0.x); acc0.y = fmaf(nw1, BFHI(U.x), acc0.y);
        acc0.z = fmaf(nw1, BFLO(U.y), acc0.z); acc0.w = fmaf(nw1, BFHI(U.y), acc0.w);
        acc1.x = fmaf(nw1, BFLO(U.z), acc1.x); acc1.y = fmaf(nw1, BFHI(U.z), acc1.y);
        acc1.z = fmaf(nw1, BFLO(U.w), acc1.z); acc1.w = fmaf(nw1, BFHI(U.w), acc1.w);
    }

    // combine the 4 edge-groups: sum over lanes {cl, cl+16, cl+32, cl+48}
    #pragma unroll
    for (int m = 16; m <= 32; m <<= 1) {
        acc0.x += __shfl_xor(acc0.x, m); acc0.y += __shfl_xor(acc0.y, m);
        acc0.z += __shfl_xor(acc0.z, m); acc0.w += __shfl_xor(acc0.w, m);
        acc1.x += __shfl_xor(acc1.x, m); acc1.y += __shfl_xor(acc1.y, m);
        acc1.z += __shfl_xor(acc1.z, m); acc1.w += __shfl_xor(acc1.w, m);
    }

    if (g == 0) {
        const float4* bp = (const float4*)(bias + cl * 8);
        float4 bv0 = bp[0], bv1 = bp[1];
        acc0.x = fmaf(acc0.x, di, bv0.x); acc0.y = fmaf(acc0.y, di, bv0.y);
        acc0.z = fmaf(acc0.z, di, bv0.z); acc0.w = fmaf(acc0.w, di, bv0.w);
        acc1.x = fmaf(acc1.x, di, bv1.x); acc1.y = fmaf(acc1.y, di, bv1.y);
        acc1.z = fmaf(acc1.z, di, bv1.z); acc1.w = fmaf(acc1.w, di, bv1.w);
        if (RELU) {
            acc0.x = fmaxf(acc0.x, 0.f); acc0.y = fmaxf(acc0.y, 0.f);
            acc0.z = fmaxf(acc0.z, 0.f); acc0.w = fmaxf(acc0.w, 0.f);
            acc1.x = fmaxf(acc1.x, 0.f); acc1.y = fmaxf(acc1.y, 0.f);
            acc1.z = fmaxf(acc1.z, 0.f); acc1.w = fmaxf(acc1.w, 0.f);
        }
        float4* op = (float4*)(out + (size_t)node * NC + cl * 8);
        op[0] = acc0;
        op[1] = acc1;
    }
}

// ---------------- launch ----------------

static inline size_t alignup(size_t x) { return (x + 255) & ~(size_t)255; }

extern "C" void kernel_launch(void* const* d_in, const int* in_sizes, int n_in,
                              void* d_out, int out_size, void* d_ws, size_t ws_size,
                              hipStream_t stream) {
    const float* X  = (const float*)d_in[0];
    const int*   ei = (const int*)d_in[1];          // [2, NE]: row0 = src, row1 = dst
    const float* ew = (const float*)d_in[2];
    const float* W1 = (const float*)d_in[3]; const float* b1 = (const float*)d_in[4];
    const float* W2 = (const float*)d_in[5]; const float* b2 = (const float*)d_in[6];
    const float* W3 = (const float*)d_in[7]; const float* b3 = (const float*)d_in[8];
    float* out = (float*)d_out;

    const int* srcp = ei;
    const int* dstp = ei + NE;

    // workspace carve
    char* w = (char*)d_ws;
    size_t need = 0;
    auto carve = [&](size_t bytes) { char* p = w + need; need += alignup(bytes); return p; };
    float* dinv     = (float*)carve(NN * 4);
    int*   cnt      = (int*)  carve(NN * 4);
    int*   rowstart = (int*)  carve((NN + 1) * 4);
    int*   bsum     = (int*)  carve(NB * 4);
    int*   slot     = (int*)  carve((size_t)NE * 4);
    int2*  edat     = (int2*) carve((size_t)NE * 8);
    unsigned short* Hb = (unsigned short*)carve((size_t)NN * NC * 2);
    float* A        = (float*)carve((size_t)NN * NC * 4);
    if (need > ws_size) return;  // workspace too small -> visible validation failure

    const int gN  = (NN + 255) / 256;
    const int gE  = (NE + 255) / 256;
    const int gE4 = (NE / 4 + 255) / 256;
    const int gGemm = (NN + 127) / 128;
    const int gAgg  = (NN * 64 + 255) / 256;  // one wave per node

    // build normalization + CSR (once; reused by all 3 layers)
    k_init<<<gN, 256, 0, stream>>>(cnt);
    k_count<<<gE4, 256, 0, stream>>>((const int4*)dstp, cnt, (int4*)slot);
    k_scan1<<<NB, 256, 0, stream>>>(cnt, bsum);
    k_scan2<<<1, 64, 0, stream>>>(bsum, rowstart);
    k_scan3<<<NB, 256, 0, stream>>>(cnt, bsum, rowstart);
    k_fill<<<gE4, 256, 0, stream>>>((const int4*)srcp, (const int4*)dstp, (const float4*)ew,
                                    rowstart, (const int4*)slot, edat);
    k_degdinv<<<gN, 256, 0, stream>>>(rowstart, edat, dinv);
    k_norm<<<gE, 256, 0, stream>>>(dinv, edat);

    // layer 1
    k_gemm<<<gGemm, 256, 0, stream>>>(X, W1, Hb);
    k_agg<1><<<gAgg, 256, 0, stream>>>(Hb, rowstart, edat, dinv, b1, A);
    // layer 2
    k_gemm<<<gGemm, 256, 0, stream>>>(A, W2, Hb);
    k_agg<1><<<gAgg, 256, 0, stream>>>(Hb, rowstart, edat, dinv, b2, A);
    // layer 3
    k_gemm<<<gGemm, 256, 0, stream>>>(A, W3, Hb);
    k_agg<0><<<gAgg, 256, 0, stream>>>(Hb, rowstart, edat, dinv, b3, out);
}

// Round 8
// 517.991 us; speedup vs baseline: 1.3251x; 1.0025x over previous
//
#include <hip/hip_runtime.h>
#include <hip/hip_bf16.h>
#include <cstdint>

#define NN 100000
#define NE 1600000
#define NC 128

constexpr int SCAN_SEG = 1024;
constexpr int NB = (NN + SCAN_SEG - 1) / SCAN_SEG; // 98

// ---------------- bf16 helpers ----------------

__device__ __forceinline__ unsigned short f2bf(float f) {
    unsigned int u = __float_as_uint(f);
    u = (u + 0x7fffu + ((u >> 16) & 1u)) >> 16;   // RNE
    return (unsigned short)u;
}
#define BFLO(u) __uint_as_float((u) << 16)
#define BFHI(u) __uint_as_float((u) & 0xffff0000u)

// ---------------- CSR build ----------------

__global__ __launch_bounds__(256) void k_init(int* __restrict__ cnt) {
    int i = blockIdx.x * 256 + threadIdx.x;
    if (i < NN) cnt[i] = 0;
}

// ---------------- fused: layer-1 GEMM + edge count ----------------
// Blocks [0, nCnt): one int atomic per edge, old value = within-row slot
// (atomic-latency-bound, VALU idle). Blocks [nCnt, nCnt+gGemm): Hb = bf16(X@W1)
// (VALU-bound). Independent outputs; overlap hides the atomic latency.

__global__ __launch_bounds__(256) void k_gemm1_count(const float* __restrict__ Xg, const float* __restrict__ Wg,
                                                     unsigned short* __restrict__ Hb,
                                                     const int4* __restrict__ dst4, int* __restrict__ cnt,
                                                     int4* __restrict__ slot4, int nCnt) {
    __shared__ float Xs[32][128];  // [k][row] 16 KB
    __shared__ float Ws[32][128];  // [k][col] 16 KB

    if ((int)blockIdx.x < nCnt) {
        int i = blockIdx.x * 256 + threadIdx.x;
        if (i < NE / 4) {
            int4 d = dst4[i];
            int4 s;
            s.x = atomicAdd(&cnt[d.x], 1);
            s.y = atomicAdd(&cnt[d.y], 1);
            s.z = atomicAdd(&cnt[d.z], 1);
            s.w = atomicAdd(&cnt[d.w], 1);
            slot4[i] = s;
        }
        return;
    }

    int t  = threadIdx.x;
    int tx = t & 15;
    int ty = t >> 4;
    int rowBase = (blockIdx.x - nCnt) * 128;

    float4 accA[8], accB[8];
    #pragma unroll
    for (int r = 0; r < 8; ++r) { accA[r] = make_float4(0.f,0.f,0.f,0.f); accB[r] = accA[r]; }

    int lrow = t & 127;
    int lq   = t >> 7;
    int gr = rowBase + lrow; if (gr > NN - 1) gr = NN - 1;
    const float* xp = Xg + (size_t)gr * NC + lq * 16;

    for (int kc = 0; kc < 128; kc += 32) {
        float4 xa = *(const float4*)(xp + kc + 0);
        float4 xb = *(const float4*)(xp + kc + 4);
        float4 xc = *(const float4*)(xp + kc + 8);
        float4 xd = *(const float4*)(xp + kc + 12);
        float4 wl[4];
        #pragma unroll
        for (int j = 0; j < 4; ++j) {
            int l = (t + j * 256) * 4;
            wl[j] = *(const float4*)&Wg[(size_t)(kc + (l >> 7)) * NC + (l & 127)];
        }
        __syncthreads();
        int kb = lq * 16;
        Xs[kb+ 0][lrow] = xa.x; Xs[kb+ 1][lrow] = xa.y; Xs[kb+ 2][lrow] = xa.z; Xs[kb+ 3][lrow] = xa.w;
        Xs[kb+ 4][lrow] = xb.x; Xs[kb+ 5][lrow] = xb.y; Xs[kb+ 6][lrow] = xb.z; Xs[kb+ 7][lrow] = xb.w;
        Xs[kb+ 8][lrow] = xc.x; Xs[kb+ 9][lrow] = xc.y; Xs[kb+10][lrow] = xc.z; Xs[kb+11][lrow] = xc.w;
        Xs[kb+12][lrow] = xd.x; Xs[kb+13][lrow] = xd.y; Xs[kb+14][lrow] = xd.z; Xs[kb+15][lrow] = xd.w;
        #pragma unroll
        for (int j = 0; j < 4; ++j) {
            int l = (t + j * 256) * 4;
            *(float4*)&Ws[l >> 7][l & 127] = wl[j];
        }
        __syncthreads();

        #pragma unroll 8
        for (int k = 0; k < 32; ++k) {
            float4 wv0 = *(const float4*)&Ws[k][tx * 4];
            float4 wv1 = *(const float4*)&Ws[k][64 + tx * 4];
            float4 xv0 = *(const float4*)&Xs[k][ty * 8];
            float4 xv1 = *(const float4*)&Xs[k][ty * 8 + 4];
            float xs[8] = {xv0.x, xv0.y, xv0.z, xv0.w, xv1.x, xv1.y, xv1.z, xv1.w};
            #pragma unroll
            for (int r = 0; r < 8; ++r) {
                accA[r].x = fmaf(xs[r], wv0.x, accA[r].x);
                accA[r].y = fmaf(xs[r], wv0.y, accA[r].y);
                accA[r].z = fmaf(xs[r], wv0.z, accA[r].z);
                accA[r].w = fmaf(xs[r], wv0.w, accA[r].w);
                accB[r].x = fmaf(xs[r], wv1.x, accB[r].x);
                accB[r].y = fmaf(xs[r], wv1.y, accB[r].y);
                accB[r].z = fmaf(xs[r], wv1.z, accB[r].z);
                accB[r].w = fmaf(xs[r], wv1.w, accB[r].w);
            }
        }
    }

    #pragma unroll
    for (int r = 0; r < 8; ++r) {
        int grow = rowBase + ty * 8 + r;
        if (grow < NN) {
            ushort4 oa, ob;
            oa.x = f2bf(accA[r].x); oa.y = f2bf(accA[r].y); oa.z = f2bf(accA[r].z); oa.w = f2bf(accA[r].w);
            ob.x = f2bf(accB[r].x); ob.y = f2bf(accB[r].y); ob.z = f2bf(accB[r].z); ob.w = f2bf(accB[r].w);
            *(ushort4*)&Hb[(size_t)grow * NC + tx * 4]      = oa;
            *(ushort4*)&Hb[(size_t)grow * NC + 64 + tx * 4] = ob;
        }
    }
}

// ---------------- exclusive scan of cnt -> rowstart ----------------

__global__ __launch_bounds__(256) void k_scan1(const int* __restrict__ cnt, int* __restrict__ bsum) {
    __shared__ int sdata[256];
    int b = blockIdx.x, t = threadIdx.x;
    int base = b * SCAN_SEG + t * 4;
    int s = 0;
    #pragma unroll
    for (int j = 0; j < 4; ++j) { int idx = base + j; if (idx < NN) s += cnt[idx]; }
    sdata[t] = s; __syncthreads();
    for (int off = 128; off > 0; off >>= 1) {
        if (t < off) sdata[t] += sdata[t + off];
        __syncthreads();
    }
    if (t == 0) bsum[b] = sdata[0];
}

__global__ void k_scan2(int* __restrict__ bsum, int* __restrict__ rowstart) {
    if (threadIdx.x == 0 && blockIdx.x == 0) {
        int run = 0;
        for (int i = 0; i < NB; ++i) { int v = bsum[i]; bsum[i] = run; run += v; }
        rowstart[NN] = run;  // == NE
    }
}

__global__ __launch_bounds__(256) void k_scan3(const int* __restrict__ cnt, const int* __restrict__ bsum,
                                               int* __restrict__ rowstart) {
    __shared__ int sdata[256];
    int b = blockIdx.x, t = threadIdx.x;
    int base = b * SCAN_SEG + t * 4;
    int v[4]; int vsum = 0;
    #pragma unroll
    for (int j = 0; j < 4; ++j) { int idx = base + j; v[j] = (idx < NN) ? cnt[idx] : 0; vsum += v[j]; }
    sdata[t] = vsum; __syncthreads();
    int incl = vsum;
    for (int off = 1; off < 256; off <<= 1) {
        int add = (t >= off) ? sdata[t - off] : 0;
        __syncthreads();
        incl += add;
        sdata[t] = incl;
        __syncthreads();
    }
    int run = bsum[b] + (incl - vsum);
    #pragma unroll
    for (int j = 0; j < 4; ++j) {
        int idx = base + j;
        if (idx < NN) { rowstart[idx] = run; run += v[j]; }
    }
}

// ---------------- CSR fill (no atomics): edat[pos] = {src, bits(RAW w)} ----------------

__global__ __launch_bounds__(256) void k_fill(const int4* __restrict__ src4, const int4* __restrict__ dst4,
                                              const float4* __restrict__ w4, const int* __restrict__ rowstart,
                                              const int4* __restrict__ slot4, int2* __restrict__ edat) {
    int i = blockIdx.x * 256 + threadIdx.x;
    if (i < NE / 4) {
        int4 s = src4[i]; int4 d = dst4[i]; float4 wv = w4[i]; int4 sl = slot4[i];
        edat[rowstart[d.x] + sl.x] = make_int2(s.x, __float_as_int(wv.x));
        edat[rowstart[d.y] + sl.y] = make_int2(s.y, __float_as_int(wv.y));
        edat[rowstart[d.z] + sl.z] = make_int2(s.z, __float_as_int(wv.z));
        edat[rowstart[d.w] + sl.w] = make_int2(s.w, __float_as_int(wv.w));
    }
}

// ---------------- deg -> dinv (no atomics): deg = 1 + sum_row(w) ----------------

__global__ __launch_bounds__(256) void k_degdinv(const int* __restrict__ rs, const int2* __restrict__ edat,
                                                 float* __restrict__ dinv) {
    int i = blockIdx.x * 256 + threadIdx.x;
    if (i < NN) {
        float dg = 1.0f;  // self-loop weight
        int p1 = rs[i + 1];
        for (int p = rs[i]; p < p1; ++p) dg += __int_as_float(edat[p].y);
        dinv[i] = (dg > 0.0f) ? (1.0f / sqrtf(fmaxf(dg, 1e-12f))) : 0.0f;
    }
}

// ---------------- norm: edat[p].y = bits(dinv[src] * w)  (dinv[dst] applied in k_agg) ----------------

__global__ __launch_bounds__(256) void k_norm(const float* __restrict__ dinv, int2* __restrict__ edat) {
    int p = blockIdx.x * 256 + threadIdx.x;
    if (p < NE) {
        int2 ed = edat[p];
        edat[p].y = __float_as_int(dinv[ed.x] * __int_as_float(ed.y));
    }
}

// ---------------- GEMM: Hb = bf16(X @ W) (layers 2,3) ----------------

__global__ __launch_bounds__(256) void k_gemm(const float* __restrict__ Xg, const float* __restrict__ Wg,
                                              unsigned short* __restrict__ Hb) {
    __shared__ float Xs[32][128];  // [k][row] 16 KB
    __shared__ float Ws[32][128];  // [k][col] 16 KB

    int t  = threadIdx.x;
    int tx = t & 15;
    int ty = t >> 4;
    int rowBase = blockIdx.x * 128;

    float4 accA[8], accB[8];
    #pragma unroll
    for (int r = 0; r < 8; ++r) { accA[r] = make_float4(0.f,0.f,0.f,0.f); accB[r] = accA[r]; }

    int lrow = t & 127;
    int lq   = t >> 7;
    int gr = rowBase + lrow; if (gr > NN - 1) gr = NN - 1;
    const float* xp = Xg + (size_t)gr * NC + lq * 16;

    for (int kc = 0; kc < 128; kc += 32) {
        float4 xa = *(const float4*)(xp + kc + 0);
        float4 xb = *(const float4*)(xp + kc + 4);
        float4 xc = *(const float4*)(xp + kc + 8);
        float4 xd = *(const float4*)(xp + kc + 12);
        float4 wl[4];
        #pragma unroll
        for (int j = 0; j < 4; ++j) {
            int l = (t + j * 256) * 4;
            wl[j] = *(const float4*)&Wg[(size_t)(kc + (l >> 7)) * NC + (l & 127)];
        }
        __syncthreads();
        int kb = lq * 16;
        Xs[kb+ 0][lrow] = xa.x; Xs[kb+ 1][lrow] = xa.y; Xs[kb+ 2][lrow] = xa.z; Xs[kb+ 3][lrow] = xa.w;
        Xs[kb+ 4][lrow] = xb.x; Xs[kb+ 5][lrow] = xb.y; Xs[kb+ 6][lrow] = xb.z; Xs[kb+ 7][lrow] = xb.w;
        Xs[kb+ 8][lrow] = xc.x; Xs[kb+ 9][lrow] = xc.y; Xs[kb+10][lrow] = xc.z; Xs[kb+11][lrow] = xc.w;
        Xs[kb+12][lrow] = xd.x; Xs[kb+13][lrow] = xd.y; Xs[kb+14][lrow] = xd.z; Xs[kb+15][lrow] = xd.w;
        #pragma unroll
        for (int j = 0; j < 4; ++j) {
            int l = (t + j * 256) * 4;
            *(float4*)&Ws[l >> 7][l & 127] = wl[j];
        }
        __syncthreads();

        #pragma unroll 8
        for (int k = 0; k < 32; ++k) {
            float4 wv0 = *(const float4*)&Ws[k][tx * 4];
            float4 wv1 = *(const float4*)&Ws[k][64 + tx * 4];
            float4 xv0 = *(const float4*)&Xs[k][ty * 8];
            float4 xv1 = *(const float4*)&Xs[k][ty * 8 + 4];
            float xs[8] = {xv0.x, xv0.y, xv0.z, xv0.w, xv1.x, xv1.y, xv1.z, xv1.w};
            #pragma unroll
            for (int r = 0; r < 8; ++r) {
                accA[r].x = fmaf(xs[r], wv0.x, accA[r].x);
                accA[r].y = fmaf(xs[r], wv0.y, accA[r].y);
                accA[r].z = fmaf(xs[r], wv0.z, accA[r].z);
                accA[r].w = fmaf(xs[r], wv0.w, accA[r].w);
                accB[r].x = fmaf(xs[r], wv1.x, accB[r].x);
                accB[r].y = fmaf(xs[r], wv1.y, accB[r].y);
                accB[r].z = fmaf(xs[r], wv1.z, accB[r].z);
                accB[r].w = fmaf(xs[r], wv1.w, accB[r].w);
            }
        }
    }

    #pragma unroll
    for (int r = 0; r < 8; ++r) {
        int grow = rowBase + ty * 8 + r;
        if (grow < NN) {
            ushort4 oa, ob;
            oa.x = f2bf(accA[r].x); oa.y = f2bf(accA[r].y); oa.z = f2bf(accA[r].z); oa.w = f2bf(accA[r].w);
            ob.x = f2bf(accB[r].x); ob.y = f2bf(accB[r].y); ob.z = f2bf(accB[r].z); ob.w = f2bf(accB[r].w);
            *(ushort4*)&Hb[(size_t)grow * NC + tx * 4]      = oa;
            *(ushort4*)&Hb[(size_t)grow * NC + 64 + tx * 4] = ob;
        }
    }
}

// ---------------- aggregation ----------------
// One 64-lane wave per node. 4 edge-groups x 16 lanes; each lane owns 8 channels
// (one dwordx4 of bf16 per edge). 4-way unrolled edge walk -> up to 16 edges in
// flight per wave. out[d] = dinv[d]*(sum_e nrm'*Hb[s] + dinv[d]*Hb[d]) + b.

#define AGG_FMA8(NW, U)                                                                    \
    do {                                                                                   \
        acc0.x = fmaf((NW), BFLO((U).x), acc0.x); acc0.y = fmaf((NW), BFHI((U).x), acc0.y);\
        acc0.z = fmaf((NW), BFLO((U).y), acc0.z); acc0.w = fmaf((NW), BFHI((U).y), acc0.w);\
        acc1.x = fmaf((NW), BFLO((U).z), acc1.x); acc1.y = fmaf((NW), BFHI((U).z), acc1.y);\
        acc1.z = fmaf((NW), BFLO((U).w), acc1.z); acc1.w = fmaf((NW), BFHI((U).w), acc1.w);\
    } while (0)

template <int RELU>
__global__ __launch_bounds__(256) void k_agg(const unsigned short* __restrict__ Hb, const int* __restrict__ rs,
                                             const int2* __restrict__ edat,
                                             const float* __restrict__ dinv, const float* __restrict__ bias,
                                             float* __restrict__ out) {
    int wid  = (blockIdx.x * 256 + threadIdx.x) >> 6;
    int lane = threadIdx.x & 63;
    if (wid >= NN) return;
    int node = wid;
    int g  = lane >> 4;   // edge group 0..3
    int cl = lane & 15;   // channel lane: owns channels cl*8 .. cl*8+7

    float di = dinv[node];
    float4 acc0 = make_float4(0.f, 0.f, 0.f, 0.f);
    float4 acc1 = make_float4(0.f, 0.f, 0.f, 0.f);

    // self-loop contribution (before the final *di): di * H[node]
    if (g == 0) {
        uint4 U = *(const uint4*)(Hb + (size_t)node * NC + cl * 8);
        acc0.x = BFLO(U.x) * di; acc0.y = BFHI(U.x) * di;
        acc0.z = BFLO(U.y) * di; acc0.w = BFHI(U.y) * di;
        acc1.x = BFLO(U.z) * di; acc1.y = BFHI(U.z) * di;
        acc1.z = BFLO(U.w) * di; acc1.w = BFHI(U.w) * di;
    }

    int p0 = rs[node], p1 = rs[node + 1];
    int p = p0 + g;
    for (; p + 12 < p1; p += 16) {
        long long r1 = __builtin_nontemporal_load((const long long*)&edat[p]);
        long long r2 = __builtin_nontemporal_load((const long long*)&edat[p + 4]);
        long long r3 = __builtin_nontemporal_load((const long long*)&edat[p + 8]);
        long long r4 = __builtin_nontemporal_load((const long long*)&edat[p + 12]);
        int   s1 = (int)(r1 & 0xffffffffLL);  float nw1 = __int_as_float((int)(r1 >> 32));
        int   s2 = (int)(r2 & 0xffffffffLL);  float nw2 = __int_as_float((int)(r2 >> 32));
        int   s3 = (int)(r3 & 0xffffffffLL);  float nw3 = __int_as_float((int)(r3 >> 32));
        int   s4 = (int)(r4 & 0xffffffffLL);  float nw4 = __int_as_float((int)(r4 >> 32));
        uint4 U1 = *(const uint4*)(Hb + (size_t)s1 * NC + cl * 8);
        uint4 U2 = *(const uint4*)(Hb + (size_t)s2 * NC + cl * 8);
        uint4 U3 = *(const uint4*)(Hb + (size_t)s3 * NC + cl * 8);
        uint4 U4 = *(const uint4*)(Hb + (size_t)s4 * NC + cl * 8);
        AGG_FMA8(nw1, U1);
        AGG_FMA8(nw2, U2);
        AGG_FMA8(nw3, U3);
        AGG_FMA8(nw4, U4);
    }
    for (; p < p1; p += 4) {
        long long r1 = __builtin_nontemporal_load((const long long*)&edat[p]);
        int   s1 = (int)(r1 & 0xffffffffLL);  float nw1 = __int_as_float((int)(r1 >> 32));
        uint4 U1 = *(const uint4*)(Hb + (size_t)s1 * NC + cl * 8);
        AGG_FMA8(nw1, U1);
    }

    // combine the 4 edge-groups: sum over lanes {cl, cl+16, cl+32, cl+48}
    #pragma unroll
    for (int m = 16; m <= 32; m <<= 1) {
        acc0.x += __shfl_xor(acc0.x, m); acc0.y += __shfl_xor(acc0.y, m);
        acc0.z += __shfl_xor(acc0.z, m); acc0.w += __shfl_xor(acc0.w, m);
        acc1.x += __shfl_xor(acc1.x, m); acc1.y += __shfl_xor(acc1.y, m);
        acc1.z += __shfl_xor(acc1.z, m); acc1.w += __shfl_xor(acc1.w, m);
    }

    if (g == 0) {
        const float4* bp = (const float4*)(bias + cl * 8);
        float4 bv0 = bp[0], bv1 = bp[1];
        acc0.x = fmaf(acc0.x, di, bv0.x); acc0.y = fmaf(acc0.y, di, bv0.y);
        acc0.z = fmaf(acc0.z, di, bv0.z); acc0.w = fmaf(acc0.w, di, bv0.w);
        acc1.x = fmaf(acc1.x, di, bv1.x); acc1.y = fmaf(acc1.y, di, bv1.y);
        acc1.z = fmaf(acc1.z, di, bv1.z); acc1.w = fmaf(acc1.w, di, bv1.w);
        if (RELU) {
            acc0.x = fmaxf(acc0.x, 0.f); acc0.y = fmaxf(acc0.y, 0.f);
            acc0.z = fmaxf(acc0.z, 0.f); acc0.w = fmaxf(acc0.w, 0.f);
            acc1.x = fmaxf(acc1.x, 0.f); acc1.y = fmaxf(acc1.y, 0.f);
            acc1.z = fmaxf(acc1.z, 0.f); acc1.w = fmaxf(acc1.w, 0.f);
        }
        float4* op = (float4*)(out + (size_t)node * NC + cl * 8);
        op[0] = acc0;
        op[1] = acc1;
    }
}

// ---------------- launch ----------------

static inline size_t alignup(size_t x) { return (x + 255) & ~(size_t)255; }

extern "C" void kernel_launch(void* const* d_in, const int* in_sizes, int n_in,
                              void* d_out, int out_size, void* d_ws, size_t ws_size,
                              hipStream_t stream) {
    const float* X  = (const float*)d_in[0];
    const int*   ei = (const int*)d_in[1];          // [2, NE]: row0 = src, row1 = dst
    const float* ew = (const float*)d_in[2];
    const float* W1 = (const float*)d_in[3]; const float* b1 = (const float*)d_in[4];
    const float* W2 = (const float*)d_in[5]; const float* b2 = (const float*)d_in[6];
    const float* W3 = (const float*)d_in[7]; const float* b3 = (const float*)d_in[8];
    float* out = (float*)d_out;

    const int* srcp = ei;
    const int* dstp = ei + NE;

    // workspace carve
    char* w = (char*)d_ws;
    size_t need = 0;
    auto carve = [&](size_t bytes) { char* p = w + need; need += alignup(bytes); return p; };
    float* dinv     = (float*)carve(NN * 4);
    int*   cnt      = (int*)  carve(NN * 4);
    int*   rowstart = (int*)  carve((NN + 1) * 4);
    int*   bsum     = (int*)  carve(NB * 4);
    int*   slot     = (int*)  carve((size_t)NE * 4);
    int2*  edat     = (int2*) carve((size_t)NE * 8);
    unsigned short* Hb = (unsigned short*)carve((size_t)NN * NC * 2);
    float* A        = (float*)carve((size_t)NN * NC * 4);
    if (need > ws_size) return;  // workspace too small -> visible validation failure

    const int gN  = (NN + 255) / 256;
    const int gE  = (NE + 255) / 256;
    const int gE4 = (NE / 4 + 255) / 256;
    const int gGemm = (NN + 127) / 128;
    const int gAgg  = (NN * 64 + 255) / 256;  // one wave per node

    // CSR build overlapped with layer-1 GEMM
    k_init<<<gN, 256, 0, stream>>>(cnt);
    k_gemm1_count<<<gE4 + gGemm, 256, 0, stream>>>(X, W1, Hb, (const int4*)dstp, cnt, (int4*)slot, gE4);
    k_scan1<<<NB, 256, 0, stream>>>(cnt, bsum);
    k_scan2<<<1, 64, 0, stream>>>(bsum, rowstart);
    k_scan3<<<NB, 256, 0, stream>>>(cnt, bsum, rowstart);
    k_fill<<<gE4, 256, 0, stream>>>((const int4*)srcp, (const int4*)dstp, (const float4*)ew,
                                    rowstart, (const int4*)slot, edat);
    k_degdinv<<<gN, 256, 0, stream>>>(rowstart, edat, dinv);
    k_norm<<<gE, 256, 0, stream>>>(dinv, edat);

    // layer 1 aggregation
    k_agg<1><<<gAgg, 256, 0, stream>>>(Hb, rowstart, edat, dinv, b1, A);
    // layer 2
    k_gemm<<<gGemm, 256, 0, stream>>>(A, W2, Hb);
    k_agg<1><<<gAgg, 256, 0, stream>>>(Hb, rowstart, edat, dinv, b2, A);
    // layer 3
    k_gemm<<<gGemm, 256, 0, stream>>>(A, W3, Hb);
    k_agg<0><<<gAgg, 256, 0, stream>>>(Hb, rowstart, edat, dinv, b3, out);
}

// Round 9
// 511.427 us; speedup vs baseline: 1.3421x; 1.0128x over previous
//
#include <hip/hip_runtime.h>
#include <hip/hip_bf16.h>
#include <cstdint>

#define NN 100000
#define NE 1600000
#define NC 128

constexpr int SCAN_SEG = 1024;
constexpr int NB = (NN + SCAN_SEG - 1) / SCAN_SEG; // 98
constexpr int GGEMM = (NN + 127) / 128;            // 782
constexpr int CTHREADS = GGEMM * 256;              // 200192 count threads
constexpr int NE4 = NE / 4;                        // 400000

// ---------------- bf16 helpers ----------------

__device__ __forceinline__ unsigned short f2bf(float f) {
    unsigned int u = __float_as_uint(f);
    u = (u + 0x7fffu + ((u >> 16) & 1u)) >> 16;   // RNE
    return (unsigned short)u;
}
#define BFLO(u) __uint_as_float((u) << 16)
#define BFHI(u) __uint_as_float((u) & 0xffff0000u)

// ---------------- CSR build ----------------

__global__ __launch_bounds__(256) void k_init(int* __restrict__ cnt) {
    int i = blockIdx.x * 256 + threadIdx.x;
    if (i < NN) cnt[i] = 0;
}

// ---------------- fused: layer-1 GEMM with count prologue/epilogue ----------------
// Every block: (1) issue 8 edge-count atomics per thread, keep returned slots
// in registers; (2) full 128x128 GEMM tile; (3) write slot4. Wave-level vmcnt
// stalls cover only the wave's own atomics; the global 1.6M-atomic drain
// overlaps with resident waves' GEMM compute.

__global__ __launch_bounds__(256) void k_gemm1c(const float* __restrict__ Xg, const float* __restrict__ Wg,
                                                unsigned short* __restrict__ Hb,
                                                const int4* __restrict__ dst4, int* __restrict__ cnt,
                                                int4* __restrict__ slot4) {
    __shared__ float Xs[32][128];  // [k][row] 16 KB
    __shared__ float Ws[32][128];  // [k][col] 16 KB

    int t   = threadIdx.x;
    int tid = blockIdx.x * 256 + t;

    // count prologue: issue atomics, hold results
    int4 sA, sB;
    bool hasB = (tid + CTHREADS) < NE4;   // tid < NE4 always (CTHREADS < NE4)
    {
        int4 d = dst4[tid];
        sA.x = atomicAdd(&cnt[d.x], 1);
        sA.y = atomicAdd(&cnt[d.y], 1);
        sA.z = atomicAdd(&cnt[d.z], 1);
        sA.w = atomicAdd(&cnt[d.w], 1);
    }
    if (hasB) {
        int4 d = dst4[tid + CTHREADS];
        sB.x = atomicAdd(&cnt[d.x], 1);
        sB.y = atomicAdd(&cnt[d.y], 1);
        sB.z = atomicAdd(&cnt[d.z], 1);
        sB.w = atomicAdd(&cnt[d.w], 1);
    }

    int tx = t & 15;
    int ty = t >> 4;
    int rowBase = blockIdx.x * 128;

    float4 accA[8], accB[8];
    #pragma unroll
    for (int r = 0; r < 8; ++r) { accA[r] = make_float4(0.f,0.f,0.f,0.f); accB[r] = accA[r]; }

    int lrow = t & 127;
    int lq   = t >> 7;
    int gr = rowBase + lrow; if (gr > NN - 1) gr = NN - 1;
    const float* xp = Xg + (size_t)gr * NC + lq * 16;

    for (int kc = 0; kc < 128; kc += 32) {
        float4 xa = *(const float4*)(xp + kc + 0);
        float4 xb = *(const float4*)(xp + kc + 4);
        float4 xc = *(const float4*)(xp + kc + 8);
        float4 xd = *(const float4*)(xp + kc + 12);
        float4 wl[4];
        #pragma unroll
        for (int j = 0; j < 4; ++j) {
            int l = (t + j * 256) * 4;
            wl[j] = *(const float4*)&Wg[(size_t)(kc + (l >> 7)) * NC + (l & 127)];
        }
        __syncthreads();
        int kb = lq * 16;
        Xs[kb+ 0][lrow] = xa.x; Xs[kb+ 1][lrow] = xa.y; Xs[kb+ 2][lrow] = xa.z; Xs[kb+ 3][lrow] = xa.w;
        Xs[kb+ 4][lrow] = xb.x; Xs[kb+ 5][lrow] = xb.y; Xs[kb+ 6][lrow] = xb.z; Xs[kb+ 7][lrow] = xb.w;
        Xs[kb+ 8][lrow] = xc.x; Xs[kb+ 9][lrow] = xc.y; Xs[kb+10][lrow] = xc.z; Xs[kb+11][lrow] = xc.w;
        Xs[kb+12][lrow] = xd.x; Xs[kb+13][lrow] = xd.y; Xs[kb+14][lrow] = xd.z; Xs[kb+15][lrow] = xd.w;
        #pragma unroll
        for (int j = 0; j < 4; ++j) {
            int l = (t + j * 256) * 4;
            *(float4*)&Ws[l >> 7][l & 127] = wl[j];
        }
        __syncthreads();

        #pragma unroll 8
        for (int k = 0; k < 32; ++k) {
            float4 wv0 = *(const float4*)&Ws[k][tx * 4];
            float4 wv1 = *(const float4*)&Ws[k][64 + tx * 4];
            float4 xv0 = *(const float4*)&Xs[k][ty * 8];
            float4 xv1 = *(const float4*)&Xs[k][ty * 8 + 4];
            float xs[8] = {xv0.x, xv0.y, xv0.z, xv0.w, xv1.x, xv1.y, xv1.z, xv1.w};
            #pragma unroll
            for (int r = 0; r < 8; ++r) {
                accA[r].x = fmaf(xs[r], wv0.x, accA[r].x);
                accA[r].y = fmaf(xs[r], wv0.y, accA[r].y);
                accA[r].z = fmaf(xs[r], wv0.z, accA[r].z);
                accA[r].w = fmaf(xs[r], wv0.w, accA[r].w);
                accB[r].x = fmaf(xs[r], wv1.x, accB[r].x);
                accB[r].y = fmaf(xs[r], wv1.y, accB[r].y);
                accB[r].z = fmaf(xs[r], wv1.z, accB[r].z);
                accB[r].w = fmaf(xs[r], wv1.w, accB[r].w);
            }
        }
    }

    #pragma unroll
    for (int r = 0; r < 8; ++r) {
        int grow = rowBase + ty * 8 + r;
        if (grow < NN) {
            ushort4 oa, ob;
            oa.x = f2bf(accA[r].x); oa.y = f2bf(accA[r].y); oa.z = f2bf(accA[r].z); oa.w = f2bf(accA[r].w);
            ob.x = f2bf(accB[r].x); ob.y = f2bf(accB[r].y); ob.z = f2bf(accB[r].z); ob.w = f2bf(accB[r].w);
            *(ushort4*)&Hb[(size_t)grow * NC + tx * 4]      = oa;
            *(ushort4*)&Hb[(size_t)grow * NC + 64 + tx * 4] = ob;
        }
    }

    // count epilogue: write slots
    slot4[tid] = sA;
    if (hasB) slot4[tid + CTHREADS] = sB;
}

// ---------------- exclusive scan of cnt -> rowstart ----------------

__global__ __launch_bounds__(256) void k_scan1(const int* __restrict__ cnt, int* __restrict__ bsum) {
    __shared__ int sdata[256];
    int b = blockIdx.x, t = threadIdx.x;
    int base = b * SCAN_SEG + t * 4;
    int s = 0;
    #pragma unroll
    for (int j = 0; j < 4; ++j) { int idx = base + j; if (idx < NN) s += cnt[idx]; }
    sdata[t] = s; __syncthreads();
    for (int off = 128; off > 0; off >>= 1) {
        if (t < off) sdata[t] += sdata[t + off];
        __syncthreads();
    }
    if (t == 0) bsum[b] = sdata[0];
}

__global__ void k_scan2(int* __restrict__ bsum, int* __restrict__ rowstart) {
    if (threadIdx.x == 0 && blockIdx.x == 0) {
        int run = 0;
        for (int i = 0; i < NB; ++i) { int v = bsum[i]; bsum[i] = run; run += v; }
        rowstart[NN] = run;  // == NE
    }
}

__global__ __launch_bounds__(256) void k_scan3(const int* __restrict__ cnt, const int* __restrict__ bsum,
                                               int* __restrict__ rowstart) {
    __shared__ int sdata[256];
    int b = blockIdx.x, t = threadIdx.x;
    int base = b * SCAN_SEG + t * 4;
    int v[4]; int vsum = 0;
    #pragma unroll
    for (int j = 0; j < 4; ++j) { int idx = base + j; v[j] = (idx < NN) ? cnt[idx] : 0; vsum += v[j]; }
    sdata[t] = vsum; __syncthreads();
    int incl = vsum;
    for (int off = 1; off < 256; off <<= 1) {
        int add = (t >= off) ? sdata[t - off] : 0;
        __syncthreads();
        incl += add;
        sdata[t] = incl;
        __syncthreads();
    }
    int run = bsum[b] + (incl - vsum);
    #pragma unroll
    for (int j = 0; j < 4; ++j) {
        int idx = base + j;
        if (idx < NN) { rowstart[idx] = run; run += v[j]; }
    }
}

// ---------------- CSR fill (no atomics): edat[pos] = {src, bits(RAW w)} ----------------

__global__ __launch_bounds__(256) void k_fill(const int4* __restrict__ src4, const int4* __restrict__ dst4,
                                              const float4* __restrict__ w4, const int* __restrict__ rowstart,
                                              const int4* __restrict__ slot4, int2* __restrict__ edat) {
    int i = blockIdx.x * 256 + threadIdx.x;
    if (i < NE4) {
        int4 s = src4[i]; int4 d = dst4[i]; float4 wv = w4[i]; int4 sl = slot4[i];
        edat[rowstart[d.x] + sl.x] = make_int2(s.x, __float_as_int(wv.x));
        edat[rowstart[d.y] + sl.y] = make_int2(s.y, __float_as_int(wv.y));
        edat[rowstart[d.z] + sl.z] = make_int2(s.z, __float_as_int(wv.z));
        edat[rowstart[d.w] + sl.w] = make_int2(s.w, __float_as_int(wv.w));
    }
}

// ---------------- deg -> dinv (no atomics): deg = 1 + sum_row(w) ----------------

__global__ __launch_bounds__(256) void k_degdinv(const int* __restrict__ rs, const int2* __restrict__ edat,
                                                 float* __restrict__ dinv) {
    int i = blockIdx.x * 256 + threadIdx.x;
    if (i < NN) {
        float dg = 1.0f;  // self-loop weight
        int p1 = rs[i + 1];
        for (int p = rs[i]; p < p1; ++p) dg += __int_as_float(edat[p].y);
        dinv[i] = (dg > 0.0f) ? (1.0f / sqrtf(fmaxf(dg, 1e-12f))) : 0.0f;
    }
}

// ---------------- norm: edat[p].y = bits(dinv[src] * w)  (dinv[dst] applied in k_agg) ----------------

__global__ __launch_bounds__(256) void k_norm(const float* __restrict__ dinv, int2* __restrict__ edat) {
    int p = blockIdx.x * 256 + threadIdx.x;
    if (p < NE) {
        int2 ed = edat[p];
        edat[p].y = __float_as_int(dinv[ed.x] * __int_as_float(ed.y));
    }
}

// ---------------- GEMM: Hb = bf16(X @ W) (layers 2,3) ----------------

__global__ __launch_bounds__(256) void k_gemm(const float* __restrict__ Xg, const float* __restrict__ Wg,
                                              unsigned short* __restrict__ Hb) {
    __shared__ float Xs[32][128];  // [k][row] 16 KB
    __shared__ float Ws[32][128];  // [k][col] 16 KB

    int t  = threadIdx.x;
    int tx = t & 15;
    int ty = t >> 4;
    int rowBase = blockIdx.x * 128;

    float4 accA[8], accB[8];
    #pragma unroll
    for (int r = 0; r < 8; ++r) { accA[r] = make_float4(0.f,0.f,0.f,0.f); accB[r] = accA[r]; }

    int lrow = t & 127;
    int lq   = t >> 7;
    int gr = rowBase + lrow; if (gr > NN - 1) gr = NN - 1;
    const float* xp = Xg + (size_t)gr * NC + lq * 16;

    for (int kc = 0; kc < 128; kc += 32) {
        float4 xa = *(const float4*)(xp + kc + 0);
        float4 xb = *(const float4*)(xp + kc + 4);
        float4 xc = *(const float4*)(xp + kc + 8);
        float4 xd = *(const float4*)(xp + kc + 12);
        float4 wl[4];
        #pragma unroll
        for (int j = 0; j < 4; ++j) {
            int l = (t + j * 256) * 4;
            wl[j] = *(const float4*)&Wg[(size_t)(kc + (l >> 7)) * NC + (l & 127)];
        }
        __syncthreads();
        int kb = lq * 16;
        Xs[kb+ 0][lrow] = xa.x; Xs[kb+ 1][lrow] = xa.y; Xs[kb+ 2][lrow] = xa.z; Xs[kb+ 3][lrow] = xa.w;
        Xs[kb+ 4][lrow] = xb.x; Xs[kb+ 5][lrow] = xb.y; Xs[kb+ 6][lrow] = xb.z; Xs[kb+ 7][lrow] = xb.w;
        Xs[kb+ 8][lrow] = xc.x; Xs[kb+ 9][lrow] = xc.y; Xs[kb+10][lrow] = xc.z; Xs[kb+11][lrow] = xc.w;
        Xs[kb+12][lrow] = xd.x; Xs[kb+13][lrow] = xd.y; Xs[kb+14][lrow] = xd.z; Xs[kb+15][lrow] = xd.w;
        #pragma unroll
        for (int j = 0; j < 4; ++j) {
            int l = (t + j * 256) * 4;
            *(float4*)&Ws[l >> 7][l & 127] = wl[j];
        }
        __syncthreads();

        #pragma unroll 8
        for (int k = 0; k < 32; ++k) {
            float4 wv0 = *(const float4*)&Ws[k][tx * 4];
            float4 wv1 = *(const float4*)&Ws[k][64 + tx * 4];
            float4 xv0 = *(const float4*)&Xs[k][ty * 8];
            float4 xv1 = *(const float4*)&Xs[k][ty * 8 + 4];
            float xs[8] = {xv0.x, xv0.y, xv0.z, xv0.w, xv1.x, xv1.y, xv1.z, xv1.w};
            #pragma unroll
            for (int r = 0; r < 8; ++r) {
                accA[r].x = fmaf(xs[r], wv0.x, accA[r].x);
                accA[r].y = fmaf(xs[r], wv0.y, accA[r].y);
                accA[r].z = fmaf(xs[r], wv0.z, accA[r].z);
                accA[r].w = fmaf(xs[r], wv0.w, accA[r].w);
                accB[r].x = fmaf(xs[r], wv1.x, accB[r].x);
                accB[r].y = fmaf(xs[r], wv1.y, accB[r].y);
                accB[r].z = fmaf(xs[r], wv1.z, accB[r].z);
                accB[r].w = fmaf(xs[r], wv1.w, accB[r].w);
            }
        }
    }

    #pragma unroll
    for (int r = 0; r < 8; ++r) {
        int grow = rowBase + ty * 8 + r;
        if (grow < NN) {
            ushort4 oa, ob;
            oa.x = f2bf(accA[r].x); oa.y = f2bf(accA[r].y); oa.z = f2bf(accA[r].z); oa.w = f2bf(accA[r].w);
            ob.x = f2bf(accB[r].x); ob.y = f2bf(accB[r].y); ob.z = f2bf(accB[r].z); ob.w = f2bf(accB[r].w);
            *(ushort4*)&Hb[(size_t)grow * NC + tx * 4]      = oa;
            *(ushort4*)&Hb[(size_t)grow * NC + 64 + tx * 4] = ob;
        }
    }
}

// ---------------- aggregation ----------------
// One 64-lane wave per node. 4 edge-groups x 16 lanes; each lane owns 8 channels
// (one dwordx4 of bf16 per edge). 4-way unrolled edge walk -> up to 16 edges in
// flight per wave. out[d] = dinv[d]*(sum_e nrm'*Hb[s] + dinv[d]*Hb[d]) + b.

#define AGG_FMA8(NW, U)                                                                    \
    do {                                                                                   \
        acc0.x = fmaf((NW), BFLO((U).x), acc0.x); acc0.y = fmaf((NW), BFHI((U).x), acc0.y);\
        acc0.z = fmaf((NW), BFLO((U).y), acc0.z); acc0.w = fmaf((NW), BFHI((U).y), acc0.w);\
        acc1.x = fmaf((NW), BFLO((U).z), acc1.x); acc1.y = fmaf((NW), BFHI((U).z), acc1.y);\
        acc1.z = fmaf((NW), BFLO((U).w), acc1.z); acc1.w = fmaf((NW), BFHI((U).w), acc1.w);\
    } while (0)

template <int RELU>
__global__ __launch_bounds__(256) void k_agg(const unsigned short* __restrict__ Hb, const int* __restrict__ rs,
                                             const int2* __restrict__ edat,
                                             const float* __restrict__ dinv, const float* __restrict__ bias,
                                             float* __restrict__ out) {
    int wid  = (blockIdx.x * 256 + threadIdx.x) >> 6;
    int lane = threadIdx.x & 63;
    if (wid >= NN) return;
    int node = wid;
    int g  = lane >> 4;   // edge group 0..3
    int cl = lane & 15;   // channel lane: owns channels cl*8 .. cl*8+7

    float di = dinv[node];
    float4 acc0 = make_float4(0.f, 0.f, 0.f, 0.f);
    float4 acc1 = make_float4(0.f, 0.f, 0.f, 0.f);

    // self-loop contribution (before the final *di): di * H[node]
    if (g == 0) {
        uint4 U = *(const uint4*)(Hb + (size_t)node * NC + cl * 8);
        acc0.x = BFLO(U.x) * di; acc0.y = BFHI(U.x) * di;
        acc0.z = BFLO(U.y) * di; acc0.w = BFHI(U.y) * di;
        acc1.x = BFLO(U.z) * di; acc1.y = BFHI(U.z) * di;
        acc1.z = BFLO(U.w) * di; acc1.w = BFHI(U.w) * di;
    }

    int p0 = rs[node], p1 = rs[node + 1];
    int p = p0 + g;
    for (; p + 12 < p1; p += 16) {
        long long r1 = __builtin_nontemporal_load((const long long*)&edat[p]);
        long long r2 = __builtin_nontemporal_load((const long long*)&edat[p + 4]);
        long long r3 = __builtin_nontemporal_load((const long long*)&edat[p + 8]);
        long long r4 = __builtin_nontemporal_load((const long long*)&edat[p + 12]);
        int   s1 = (int)(r1 & 0xffffffffLL);  float nw1 = __int_as_float((int)(r1 >> 32));
        int   s2 = (int)(r2 & 0xffffffffLL);  float nw2 = __int_as_float((int)(r2 >> 32));
        int   s3 = (int)(r3 & 0xffffffffLL);  float nw3 = __int_as_float((int)(r3 >> 32));
        int   s4 = (int)(r4 & 0xffffffffLL);  float nw4 = __int_as_float((int)(r4 >> 32));
        uint4 U1 = *(const uint4*)(Hb + (size_t)s1 * NC + cl * 8);
        uint4 U2 = *(const uint4*)(Hb + (size_t)s2 * NC + cl * 8);
        uint4 U3 = *(const uint4*)(Hb + (size_t)s3 * NC + cl * 8);
        uint4 U4 = *(const uint4*)(Hb + (size_t)s4 * NC + cl * 8);
        AGG_FMA8(nw1, U1);
        AGG_FMA8(nw2, U2);
        AGG_FMA8(nw3, U3);
        AGG_FMA8(nw4, U4);
    }
    for (; p < p1; p += 4) {
        long long r1 = __builtin_nontemporal_load((const long long*)&edat[p]);
        int   s1 = (int)(r1 & 0xffffffffLL);  float nw1 = __int_as_float((int)(r1 >> 32));
        uint4 U1 = *(const uint4*)(Hb + (size_t)s1 * NC + cl * 8);
        AGG_FMA8(nw1, U1);
    }

    // combine the 4 edge-groups: sum over lanes {cl, cl+16, cl+32, cl+48}
    #pragma unroll
    for (int m = 16; m <= 32; m <<= 1) {
        acc0.x += __shfl_xor(acc0.x, m); acc0.y += __shfl_xor(acc0.y, m);
        acc0.z += __shfl_xor(acc0.z, m); acc0.w += __shfl_xor(acc0.w, m);
        acc1.x += __shfl_xor(acc1.x, m); acc1.y += __shfl_xor(acc1.y, m);
        acc1.z += __shfl_xor(acc1.z, m); acc1.w += __shfl_xor(acc1.w, m);
    }

    if (g == 0) {
        const float4* bp = (const float4*)(bias + cl * 8);
        float4 bv0 = bp[0], bv1 = bp[1];
        acc0.x = fmaf(acc0.x, di, bv0.x); acc0.y = fmaf(acc0.y, di, bv0.y);
        acc0.z = fmaf(acc0.z, di, bv0.z); acc0.w = fmaf(acc0.w, di, bv0.w);
        acc1.x = fmaf(acc1.x, di, bv1.x); acc1.y = fmaf(acc1.y, di, bv1.y);
        acc1.z = fmaf(acc1.z, di, bv1.z); acc1.w = fmaf(acc1.w, di, bv1.w);
        if (RELU) {
            acc0.x = fmaxf(acc0.x, 0.f); acc0.y = fmaxf(acc0.y, 0.f);
            acc0.z = fmaxf(acc0.z, 0.f); acc0.w = fmaxf(acc0.w, 0.f);
            acc1.x = fmaxf(acc1.x, 0.f); acc1.y = fmaxf(acc1.y, 0.f);
            acc1.z = fmaxf(acc1.z, 0.f); acc1.w = fmaxf(acc1.w, 0.f);
        }
        float4* op = (float4*)(out + (size_t)node * NC + cl * 8);
        op[0] = acc0;
        op[1] = acc1;
    }
}

// ---------------- launch ----------------

static inline size_t alignup(size_t x) { return (x + 255) & ~(size_t)255; }

extern "C" void kernel_launch(void* const* d_in, const int* in_sizes, int n_in,
                              void* d_out, int out_size, void* d_ws, size_t ws_size,
                              hipStream_t stream) {
    const float* X  = (const float*)d_in[0];
    const int*   ei = (const int*)d_in[1];          // [2, NE]: row0 = src, row1 = dst
    const float* ew = (const float*)d_in[2];
    const float* W1 = (const float*)d_in[3]; const float* b1 = (const float*)d_in[4];
    const float* W2 = (const float*)d_in[5]; const float* b2 = (const float*)d_in[6];
    const float* W3 = (const float*)d_in[7]; const float* b3 = (const float*)d_in[8];
    float* out = (float*)d_out;

    const int* srcp = ei;
    const int* dstp = ei + NE;

    // workspace carve
    char* w = (char*)d_ws;
    size_t need = 0;
    auto carve = [&](size_t bytes) { char* p = w + need; need += alignup(bytes); return p; };
    float* dinv     = (float*)carve(NN * 4);
    int*   cnt      = (int*)  carve(NN * 4);
    int*   rowstart = (int*)  carve((NN + 1) * 4);
    int*   bsum     = (int*)  carve(NB * 4);
    int*   slot     = (int*)  carve((size_t)NE * 4);
    int2*  edat     = (int2*) carve((size_t)NE * 8);
    unsigned short* Hb = (unsigned short*)carve((size_t)NN * NC * 2);
    float* A        = (float*)carve((size_t)NN * NC * 4);
    if (need > ws_size) return;  // workspace too small -> visible validation failure

    const int gN  = (NN + 255) / 256;
    const int gE  = (NE + 255) / 256;
    const int gE4 = (NE4 + 255) / 256;
    const int gAgg = (NN * 64 + 255) / 256;  // one wave per node

    // CSR count overlapped with layer-1 GEMM (prologue/epilogue fusion)
    k_init<<<gN, 256, 0, stream>>>(cnt);
    k_gemm1c<<<GGEMM, 256, 0, stream>>>(X, W1, Hb, (const int4*)dstp, cnt, (int4*)slot);
    k_scan1<<<NB, 256, 0, stream>>>(cnt, bsum);
    k_scan2<<<1, 64, 0, stream>>>(bsum, rowstart);
    k_scan3<<<NB, 256, 0, stream>>>(cnt, bsum, rowstart);
    k_fill<<<gE4, 256, 0, stream>>>((const int4*)srcp, (const int4*)dstp, (const float4*)ew,
                                    rowstart, (const int4*)slot, edat);
    k_degdinv<<<gN, 256, 0, stream>>>(rowstart, edat, dinv);
    k_norm<<<gE, 256, 0, stream>>>(dinv, edat);

    // layer 1 aggregation
    k_agg<1><<<gAgg, 256, 0, stream>>>(Hb, rowstart, edat, dinv, b1, A);
    // layer 2
    k_gemm<<<GGEMM, 256, 0, stream>>>(A, W2, Hb);
    k_agg<1><<<gAgg, 256, 0, stream>>>(Hb, rowstart, edat, dinv, b2, A);
    // layer 3
    k_gemm<<<GGEMM, 256, 0, stream>>>(A, W3, Hb);
    k_agg<0><<<gAgg, 256, 0, stream>>>(Hb, rowstart, edat, dinv, b3, out);
}